// Round 12
// baseline (255.120 us; speedup 1.0000x reference)
//
#include <hip/hip_runtime.h>
#include <hip/hip_bf16.h>

#define NT   49152   // Ps*B*C*L tokens
#define D_   512
#define DF_  2048
#define PS   6
#define BB   16
#define CC   8
#define LL   64
#define PREDN 96
#define NG   768     // Ps*B*C groups (tokens at l=63)

typedef unsigned short ushort_t;
using bf16x8 = __attribute__((ext_vector_type(8))) short;
using f32x4  = __attribute__((ext_vector_type(4))) float;

__device__ __forceinline__ float bf2f(unsigned short u) {
  return __uint_as_float((unsigned)u << 16);
}
__device__ __forceinline__ unsigned short f2bf(float f) {
  unsigned u = __float_as_uint(f);
  return (unsigned short)((u + 0x7fffu + ((u >> 16) & 1u)) >> 16);  // RNE
}
__device__ __forceinline__ void unp2(int x, float& a, float& b) {
  a = __uint_as_float((unsigned)x << 16);
  b = __uint_as_float((unsigned)x & 0xffff0000u);
}
__device__ __forceinline__ void gload16(const void* g, void* l) {
  __builtin_amdgcn_global_load_lds(
      (const __attribute__((address_space(1))) unsigned*)g,
      (__attribute__((address_space(3))) unsigned*)l, 16, 0, 0);
}

// ---------------------------------------------------------------------------
// bf16 MFMA GEMM, counted-vmcnt pipelined. (proven round-7 kernel, unchanged)
// C[M,N] = A[M,K] @ Bt[N,K]^T + bias, bf16 out.
// BM=256, BN=128, BK=32, 512 threads = 8 waves (4M x 2N), per-wave 64x64.
// ---------------------------------------------------------------------------
template <bool RELU>
__global__ __launch_bounds__(512, 2) void gemm_mfma(
    const ushort_t* __restrict__ A,   // [M,K] bf16 row-major
    const ushort_t* __restrict__ Bt,  // [N,K] bf16 row-major
    const float* __restrict__ bias,
    ushort_t* __restrict__ C,         // [M,N] bf16
    int M, int N, int K) {
  __shared__ __align__(16) char smem[73728];
  short* lds = (short*)smem;
  const int tid = threadIdx.x;
  const int lane = tid & 63;
  const int w = tid >> 6;       // 0..7
  const int wm = w >> 1;        // 0..3
  const int wn = w & 1;         // 0..1
  const int l15 = lane & 15, l4 = lane >> 4;

  const int nbn = N >> 7;
  const int nwg = gridDim.x;
  const int qq = nwg >> 3, rr = nwg & 7;
  const int xcd = blockIdx.x & 7, within = blockIdx.x >> 3;
  const int wg = (xcd < rr ? xcd * (qq + 1) : rr * (qq + 1) + (xcd - rr) * qq) + within;
  const int bn = (wg % nbn) << 7;
  const int bm = (wg / nbn) << 8;

  const int NKT = K >> 5;

  const int ciA0 = w * 64 + lane;
  const int ciA1 = 512 + w * 64 + lane;
  const int ciB  = w * 64 + lane;
  const int rA0 = ciA0 >> 2, rA1 = ciA1 >> 2, rB = ciB >> 2;
  const int jA0 = (ciA0 & 3) ^ ((rA0 >> 1) & 3);
  const int jA1 = (ciA1 & 3) ^ ((rA1 >> 1) & 3);
  const int jB  = (ciB  & 3) ^ ((rB  >> 1) & 3);
  const ushort_t* gA0 = A + (size_t)(bm + rA0) * K + (jA0 << 3);
  const ushort_t* gA1 = A + (size_t)(bm + rA1) * K + (jA1 << 3);
  const ushort_t* gB  = Bt + (size_t)(bn + rB) * K + (jB << 3);

  auto stage = [&](int st, int sb) {
    const int k0 = st << 5;
    gload16(gA0 + k0, smem + sb * 24576 + w * 1024);
    gload16(gA1 + k0, smem + sb * 24576 + 8192 + w * 1024);
    gload16(gB  + k0, smem + sb * 24576 + 16384 + w * 1024);
  };

  int aconst[4], bconst[4];
#pragma unroll
  for (int m = 0; m < 4; ++m) {
    int row = wm * 64 + m * 16 + l15;
    aconst[m] = row * 32 + ((l4 ^ ((row >> 1) & 3)) << 3);
  }
#pragma unroll
  for (int n = 0; n < 4; ++n) {
    int row = wn * 64 + n * 16 + l15;
    bconst[n] = 8192 + row * 32 + ((l4 ^ ((row >> 1) & 3)) << 3);
  }

  f32x4 acc[4][4] = {};

  stage(0, 0);
  stage(1, 1);

  int rb = 0, sb = 2;
  for (int kt = 0; kt < NKT; ++kt) {
    asm volatile("s_waitcnt vmcnt(3)" ::: "memory");
    __builtin_amdgcn_s_barrier();
    const short* buf = lds + rb * 12288;
    bf16x8 av[4], bv[4];
#pragma unroll
    for (int m = 0; m < 4; ++m) av[m] = *(const bf16x8*)(buf + aconst[m]);
#pragma unroll
    for (int n = 0; n < 4; ++n) bv[n] = *(const bf16x8*)(buf + bconst[n]);
    const int st = (kt + 2 < NKT) ? kt + 2 : NKT - 1;
    stage(st, sb);
    __builtin_amdgcn_s_barrier();
    __builtin_amdgcn_s_setprio(1);
#pragma unroll
    for (int m = 0; m < 4; ++m)
#pragma unroll
      for (int n = 0; n < 4; ++n)
        acc[m][n] = __builtin_amdgcn_mfma_f32_16x16x32_bf16(av[m], bv[n], acc[m][n], 0, 0, 0);
    __builtin_amdgcn_s_setprio(0);
    rb = (rb == 2) ? 0 : rb + 1;
    sb = (sb == 2) ? 0 : sb + 1;
  }

  asm volatile("s_waitcnt vmcnt(0)" ::: "memory");
  __syncthreads();

  float bc[4];
#pragma unroll
  for (int n = 0; n < 4; ++n) bc[n] = bias[bn + wn * 64 + n * 16 + l15];
  short* Cs = lds;  // [256][136] bf16
#pragma unroll
  for (int m = 0; m < 4; ++m)
#pragma unroll
    for (int n = 0; n < 4; ++n)
#pragma unroll
      for (int r2 = 0; r2 < 4; ++r2) {
        float v = acc[m][n][r2] + bc[n];
        if (RELU) v = fmaxf(v, 0.f);
        Cs[(wm * 64 + m * 16 + l4 * 4 + r2) * 136 + wn * 64 + n * 16 + l15] =
            (short)f2bf(v);
      }
  __syncthreads();
#pragma unroll
  for (int it = 0; it < 8; ++it) {
    int chunk = it * 512 + tid;
    int r = chunk >> 4;
    int c = (chunk & 15) << 3;
    int4 v = *(const int4*)(Cs + r * 136 + c);
    *(int4*)(C + (size_t)(bm + r) * N + bn + c) = v;
  }
}

// ---------------------------------------------------------------------------
// Batched transpose of the eight 512x512 weights (blockIdx.z selects).
// ---------------------------------------------------------------------------
__global__ __launch_bounds__(256) void transpose8(
    const float* s0, const float* s1, const float* s2, const float* s3,
    const float* s4, const float* s5, const float* s6, const float* s7,
    ushort_t* d0, ushort_t* d1, ushort_t* d2, ushort_t* d3,
    ushort_t* d4, ushort_t* d5, ushort_t* d6, ushort_t* d7) {
  const float* srcs[8] = {s0, s1, s2, s3, s4, s5, s6, s7};
  ushort_t* dsts[8] = {d0, d1, d2, d3, d4, d5, d6, d7};
  const float* __restrict__ W = srcs[blockIdx.z];
  ushort_t* __restrict__ Wt = dsts[blockIdx.z];
  __shared__ float tile[32][33];
  const int k0 = blockIdx.x * 32, n0 = blockIdx.y * 32;
  const int tx = threadIdx.x & 31, ty = threadIdx.x >> 5;
#pragma unroll
  for (int i = 0; i < 4; ++i)
    tile[ty + i * 8][tx] = W[(size_t)(k0 + ty + i * 8) * 512 + n0 + tx];
  __syncthreads();
#pragma unroll
  for (int i = 0; i < 4; ++i)
    Wt[(size_t)(n0 + ty + i * 8) * 512 + k0 + tx] = f2bf(tile[tx][ty + i * 8]);
}

__global__ __launch_bounds__(256) void transpose_bf16(
    const float* __restrict__ W, ushort_t* __restrict__ Wt, int K, int N) {
  __shared__ float tile[32][33];
  const int k0 = blockIdx.x * 32, n0 = blockIdx.y * 32;
  const int tx = threadIdx.x & 31, ty = threadIdx.x >> 5;
#pragma unroll
  for (int i = 0; i < 4; ++i)
    tile[ty + i * 8][tx] = W[(size_t)(k0 + ty + i * 8) * N + n0 + tx];
  __syncthreads();
#pragma unroll
  for (int i = 0; i < 4; ++i)
    Wt[(size_t)(n0 + ty + i * 8) * K + k0 + tx] = f2bf(tile[tx][ty + i * 8]);
}

// bias concat: bkv = cbk|cbv, biqkv = ibq|ibk|ibv
__global__ __launch_bounds__(256) void bias_pack(
    const float* __restrict__ cbk, const float* __restrict__ cbv,
    const float* __restrict__ ibq, const float* __restrict__ ibk,
    const float* __restrict__ ibv, float* __restrict__ bkv,
    float* __restrict__ biqkv) {
  int i = blockIdx.x * 256 + threadIdx.x;  // grid 10 -> 2560
  if (i < 512) bkv[i] = cbk[i];
  else if (i < 1024) bkv[i] = cbv[i - 512];
  else if (i < 1536) biqkv[i - 1024] = ibq[i - 1024];
  else if (i < 2048) biqkv[i - 1536 + 512] = ibk[i - 1536];
  else if (i < 2560) biqkv[i - 2048 + 1024] = ibv[i - 2048];
}

// ---------------------------------------------------------------------------
// f32 -> bf16 convert of the full token stream; also emits the gathered
// l=63 rows into G (one extra 16B store per 64 rows). Grid-strided.
// ---------------------------------------------------------------------------
__global__ __launch_bounds__(256) void conv_bf16(
    const float* __restrict__ in, ushort_t* __restrict__ out,
    ushort_t* __restrict__ G) {
  const int total = NT * D_ / 8;   // 8 bf16 per chunk
  for (int i = blockIdx.x * 256 + threadIdx.x; i < total; i += gridDim.x * 256) {
    const float4* p = (const float4*)in + (size_t)i * 2;
    float4 a = p[0], b = p[1];
    union { unsigned short u[8]; int4 v; } pk;
    pk.u[0] = f2bf(a.x); pk.u[1] = f2bf(a.y); pk.u[2] = f2bf(a.z); pk.u[3] = f2bf(a.w);
    pk.u[4] = f2bf(b.x); pk.u[5] = f2bf(b.y); pk.u[6] = f2bf(b.z); pk.u[7] = f2bf(b.w);
    ((int4*)out)[i] = pk.v;
    const int row = i >> 6;          // 64 chunks per 512-row
    if ((row & 63) == 63)            // l = 63 -> gather row
      *(int4*)(G + (size_t)(row >> 6) * 512 + (i & 63) * 8) = pk.v;
  }
}

// ---------------------------------------------------------------------------
// Single-query attention over L. Q768: [NG][512]. KV: [NT][1024]. O768: [NG][512].
// ---------------------------------------------------------------------------
__global__ __launch_bounds__(64) void attn1(
    const ushort_t* __restrict__ Q768, const ushort_t* __restrict__ KV,
    ushort_t* __restrict__ O768) {
  __shared__ float vs[64][65];
  __shared__ float qs[64];
  __shared__ float ps[64];
  const int h = blockIdx.x & 7;
  const int g = blockIdx.x >> 3;
  const int lane = threadIdx.x;
  qs[lane] = bf2f(Q768[(size_t)g * 512 + h * 64 + lane]);
  const size_t base = (size_t)g * 64 * 1024 + h * 64;
  int4 kr[8];
#pragma unroll
  for (int i = 0; i < 8; ++i)
    kr[i] = *(const int4*)(KV + base + (size_t)lane * 1024 + i * 8);
#pragma unroll
  for (int i = 0; i < 8; ++i) {
    int chunk = i * 64 + lane;
    int r = chunk >> 3, c = (chunk & 7) * 8;
    int4 vv = *(const int4*)(KV + base + (size_t)r * 1024 + 512 + c);
    const ushort_t* u = (const ushort_t*)&vv;
#pragma unroll
    for (int j = 0; j < 8; ++j) vs[r][c + j] = bf2f(u[j]);
  }
  __syncthreads();
  float s = 0.f;
  const ushort_t* ku = (const ushort_t*)kr;
#pragma unroll
  for (int d = 0; d < 64; ++d) s += qs[d] * bf2f(ku[d]);
  s *= 0.125f;
  float mx = s;
#pragma unroll
  for (int o = 32; o > 0; o >>= 1) mx = fmaxf(mx, __shfl_xor(mx, o));
  float e = __expf(s - mx);
  float sum = e;
#pragma unroll
  for (int o = 32; o > 0; o >>= 1) sum += __shfl_xor(sum, o);
  ps[lane] = e / sum;
  __syncthreads();
  float acc = 0.f;
#pragma unroll
  for (int t = 0; t < 64; ++t) acc += ps[t] * vs[t][lane];
  O768[(size_t)g * 512 + h * 64 + lane] = f2bf(acc);
}

// ---------------------------------------------------------------------------
// Attention over context axis (S=8, dh=64) on the 768-row set.
// ---------------------------------------------------------------------------
__global__ __launch_bounds__(64) void attn_ctx(
    const ushort_t* __restrict__ QKV, ushort_t* __restrict__ O) {
  __shared__ float qs[8][72], ks[8][72], vsm[8][72], ps2[8][9];
  const int h = blockIdx.x & 7;
  const int pb = blockIdx.x >> 3;   // 0..95
  const int row0 = pb * 8;
  const int tid = threadIdx.x;
  {
    int c = tid >> 3, dc = (tid & 7) * 8;
    size_t r = (size_t)(row0 + c) * 1536 + h * 64 + dc;
    int4 qv = *(const int4*)(QKV + r);
    int4 kv = *(const int4*)(QKV + r + 512);
    int4 vv = *(const int4*)(QKV + r + 1024);
    unp2(qv.x, qs[c][dc + 0], qs[c][dc + 1]); unp2(qv.y, qs[c][dc + 2], qs[c][dc + 3]);
    unp2(qv.z, qs[c][dc + 4], qs[c][dc + 5]); unp2(qv.w, qs[c][dc + 6], qs[c][dc + 7]);
    unp2(kv.x, ks[c][dc + 0], ks[c][dc + 1]); unp2(kv.y, ks[c][dc + 2], ks[c][dc + 3]);
    unp2(kv.z, ks[c][dc + 4], ks[c][dc + 5]); unp2(kv.w, ks[c][dc + 6], ks[c][dc + 7]);
    unp2(vv.x, vsm[c][dc + 0], vsm[c][dc + 1]); unp2(vv.y, vsm[c][dc + 2], vsm[c][dc + 3]);
    unp2(vv.z, vsm[c][dc + 4], vsm[c][dc + 5]); unp2(vv.w, vsm[c][dc + 6], vsm[c][dc + 7]);
  }
  __syncthreads();
  {
    int i = tid >> 3, t = tid & 7;
    float s = 0.f;
#pragma unroll
    for (int d = 0; d < 64; ++d) s += qs[i][d] * ks[t][d];
    ps2[i][t] = s * 0.125f;
  }
  __syncthreads();
  if (tid < 8) {
    float mx = -1e30f;
#pragma unroll
    for (int t = 0; t < 8; ++t) mx = fmaxf(mx, ps2[tid][t]);
    float sum = 0.f;
#pragma unroll
    for (int t = 0; t < 8; ++t) { float e = __expf(ps2[tid][t] - mx); ps2[tid][t] = e; sum += e; }
    float inv = 1.f / sum;
#pragma unroll
    for (int t = 0; t < 8; ++t) ps2[tid][t] *= inv;
  }
  __syncthreads();
#pragma unroll
  for (int c = 0; c < 8; ++c) {
    float s = 0.f;
#pragma unroll
    for (int t = 0; t < 8; ++t) s += ps2[c][t] * vsm[t][tid];
    O[(size_t)(row0 + c) * 512 + h * 64 + tid] = f2bf(s);
  }
}

// ---------------------------------------------------------------------------
// Xout(bf16) = LN(Xin_row + T) * g + b.  Xin row at blockIdx.x*in_stride+in_base.
// ---------------------------------------------------------------------------
template <bool INF32>
__global__ __launch_bounds__(256) void add_ln(
    const void* Xin, size_t in_stride, size_t in_base,
    const ushort_t* T, ushort_t* Xout,
    const float* __restrict__ g, const float* __restrict__ b) {
  const size_t off = (size_t)blockIdx.x * D_;
  const size_t ioff = (size_t)blockIdx.x * in_stride + in_base;
  const int tid = threadIdx.x;
  float x0, x1;
  if (INF32) {
    float2 xv = ((const float2*)((const float*)Xin + ioff))[tid];
    x0 = xv.x; x1 = xv.y;
  } else {
    ushort2 xv = ((const ushort2*)((const ushort_t*)Xin + ioff))[tid];
    x0 = bf2f(xv.x); x1 = bf2f(xv.y);
  }
  ushort2 tv = ((const ushort2*)(T + off))[tid];
  x0 += bf2f(tv.x);
  x1 += bf2f(tv.y);
  float s = x0 + x1, q = x0 * x0 + x1 * x1;
#pragma unroll
  for (int o = 32; o > 0; o >>= 1) { s += __shfl_down(s, o); q += __shfl_down(q, o); }
  __shared__ float ssum[4], sqsum[4];
  if ((tid & 63) == 0) { ssum[tid >> 6] = s; sqsum[tid >> 6] = q; }
  __syncthreads();
  float S = ssum[0] + ssum[1] + ssum[2] + ssum[3];
  float Qs = sqsum[0] + sqsum[1] + sqsum[2] + sqsum[3];
  float m = S * (1.f / D_);
  float var = Qs * (1.f / D_) - m * m;
  float inv = rsqrtf(var + 1e-5f);
  float y0 = (x0 - m) * inv * g[tid * 2] + b[tid * 2];
  float y1 = (x1 - m) * inv * g[tid * 2 + 1] + b[tid * 2 + 1];
  ushort2 ov; ov.x = f2bf(y0); ov.y = f2bf(y1);
  ((ushort2*)(Xout + off))[tid] = ov;
}

// ---------------------------------------------------------------------------
// Final fusion: for block (b,c), over p=0..5: LN(X768+P768 row) -> gated sum
// -> head matvec -> out[b, n, c].  Replaces add_ln + combine_last + head.
// ---------------------------------------------------------------------------
__global__ __launch_bounds__(256) void final_fuse(
    const ushort_t* __restrict__ X, const ushort_t* __restrict__ P,
    const float* __restrict__ gates,
    const float* __restrict__ g4, const float* __restrict__ b4,
    const float* __restrict__ hW, const float* __restrict__ hb,
    float* __restrict__ out) {
  __shared__ float xr[D_];
  __shared__ float ssum[4], sqsum[4];
  const int bb = blockIdx.x >> 3, cc = blockIdx.x & 7;
  const int tid = threadIdx.x;
  const float gw0 = g4[tid * 2], gw1 = g4[tid * 2 + 1];
  const float bw0 = b4[tid * 2], bw1 = b4[tid * 2 + 1];
  float a0 = 0.f, a1 = 0.f;
#pragma unroll
  for (int p = 0; p < PS; ++p) {
    const size_t row = ((size_t)(p * BB + bb) * CC + cc) * D_;
    ushort2 xv = ((const ushort2*)(X + row))[tid];
    ushort2 tv = ((const ushort2*)(P + row))[tid];
    float x0 = bf2f(xv.x) + bf2f(tv.x);
    float x1 = bf2f(xv.y) + bf2f(tv.y);
    float s = x0 + x1, q = x0 * x0 + x1 * x1;
#pragma unroll
    for (int o = 32; o > 0; o >>= 1) { s += __shfl_down(s, o); q += __shfl_down(q, o); }
    if ((tid & 63) == 0) { ssum[tid >> 6] = s; sqsum[tid >> 6] = q; }
    __syncthreads();
    float S = ssum[0] + ssum[1] + ssum[2] + ssum[3];
    float Qs = sqsum[0] + sqsum[1] + sqsum[2] + sqsum[3];
    float m = S * (1.f / D_);
    float var = Qs * (1.f / D_) - m * m;
    float inv = rsqrtf(var + 1e-5f);
    float gate = gates[bb * PS + p];
    a0 += gate * ((x0 - m) * inv * gw0 + bw0);
    a1 += gate * ((x1 - m) * inv * gw1 + bw1);
    __syncthreads();  // protect ssum/sqsum reuse
  }
  xr[tid * 2] = a0;
  xr[tid * 2 + 1] = a1;
  __syncthreads();
  if (tid < PREDN) {
    float s = hb[tid];
    for (int d = 0; d < D_; ++d) s += xr[d] * hW[d * PREDN + tid];
    out[((size_t)bb * PREDN + tid) * CC + cc] = s;
  }
}

// ---------------------------------------------------------------------------
extern "C" void kernel_launch(void* const* d_in, const int* in_sizes, int n_in,
                              void* d_out, int out_size, void* d_ws, size_t ws_size,
                              hipStream_t stream) {
  const float* ex    = (const float*)d_in[0];
  const float* gates = (const float*)d_in[1];
  const float* cWq = (const float*)d_in[2];  const float* cbq = (const float*)d_in[3];
  const float* cWk = (const float*)d_in[4];  const float* cbk = (const float*)d_in[5];
  const float* cWv = (const float*)d_in[6];  const float* cbv = (const float*)d_in[7];
  const float* cWo = (const float*)d_in[8];  const float* cbo = (const float*)d_in[9];
  const float* iWq = (const float*)d_in[10]; const float* ibq = (const float*)d_in[11];
  const float* iWk = (const float*)d_in[12]; const float* ibk = (const float*)d_in[13];
  const float* iWv = (const float*)d_in[14]; const float* ibv = (const float*)d_in[15];
  const float* iWo = (const float*)d_in[16]; const float* ibo = (const float*)d_in[17];
  const float* mW1 = (const float*)d_in[18]; const float* mb1 = (const float*)d_in[19];
  const float* mW2 = (const float*)d_in[20]; const float* mb2 = (const float*)d_in[21];
  const float* g1  = (const float*)d_in[22]; const float* b1  = (const float*)d_in[23];
  const float* g3  = (const float*)d_in[24]; const float* b3  = (const float*)d_in[25];
  const float* g4  = (const float*)d_in[26]; const float* b4  = (const float*)d_in[27];
  const float* hW  = (const float*)d_in[28]; const float* hb  = (const float*)d_in[29];
  float* out = (float*)d_out;

  // ---- workspace layout ----
  ushort_t* wq    = (ushort_t*)d_ws;           // [512][512] cWq^T
  ushort_t* wkv   = wq + 262144;               // [1024][512] cWk^T | cWv^T
  ushort_t* wo    = wkv + 524288;              // [512][512]
  ushort_t* wiqkv = wo + 262144;               // [1536][512]
  ushort_t* wio   = wiqkv + 786432;            // [512][512]
  ushort_t* w1    = wio + 262144;              // [2048][512]
  ushort_t* w2    = w1 + 1048576;              // [512][2048]
  float* bkv   = (float*)(w2 + 1048576);       // [1024] cbk|cbv
  float* biqkv = bkv + 1024;                   // [1536] ibq|ibk|ibv
  ushort_t* Xb  = (ushort_t*)(biqkv + 1536);   // [NT][512] bf16 input
  ushort_t* KVb = Xb + (size_t)NT * 512;       // [NT][1024] K|V
  ushort_t* G768   = KVb + (size_t)NT * 1024;  // [NG][512] gathered X rows
  ushort_t* Q768   = G768 + (size_t)NG * 512;  // [NG][512] projected q
  ushort_t* O768   = Q768 + (size_t)NG * 512;  // [NG][512] attn out
  ushort_t* P768   = O768 + (size_t)NG * 512;  // [NG][512] proj temp
  ushort_t* X768   = P768 + (size_t)NG * 512;  // [NG][512] residual stream
  ushort_t* QKV768 = X768 + (size_t)NG * 512;  // [NG][1536]
  ushort_t* H768   = QKV768 + (size_t)NG * 1536; // [NG][2048]

  // ---- weight/bias prep (4 launches) ----
  transpose8<<<dim3(16, 16, 8), 256, 0, stream>>>(
      cWq, cWk, cWv, cWo, iWq, iWk, iWv, iWo,
      wq, wkv, wkv + 262144, wo, wiqkv, wiqkv + 262144, wiqkv + 524288, wio);
  transpose_bf16<<<dim3(16, 64), 256, 0, stream>>>(mW1, w1, 512, 2048);
  transpose_bf16<<<dim3(64, 16), 256, 0, stream>>>(mW2, w2, 2048, 512);
  bias_pack<<<dim3(10), 256, 0, stream>>>(cbk, cbv, ibq, ibk, ibv, bkv, biqkv);

  // ---- full-width: f32->bf16 convert (+ fused l=63 gather), then K|V GEMM ----
  conv_bf16<<<dim3(2048), 256, 0, stream>>>(ex, Xb, G768);
  gemm_mfma<false><<<dim3((NT / 256) * 8), dim3(512), 0, stream>>>(
      Xb, wkv, bkv, KVb, NT, 1024, 512);

  // ---- l=63-only path (768 rows) ----
  gemm_mfma<false><<<dim3(3 * 4), dim3(512), 0, stream>>>(G768, wq, cbq, Q768, NG, 512, 512);
  attn1<<<dim3(NG * 8), dim3(64), 0, stream>>>(Q768, KVb, O768);
  gemm_mfma<false><<<dim3(3 * 4), dim3(512), 0, stream>>>(O768, wo, cbo, P768, NG, 512, 512);
  add_ln<true><<<dim3(NG), dim3(256), 0, stream>>>(
      ex, (size_t)(LL * D_), (size_t)((LL - 1) * D_), P768, X768, g1, b1);

  gemm_mfma<false><<<dim3(3 * 12), dim3(512), 0, stream>>>(X768, wiqkv, biqkv, QKV768, NG, 1536, 512);
  attn_ctx<<<dim3(96 * 8), dim3(64), 0, stream>>>(QKV768, O768);
  gemm_mfma<false><<<dim3(3 * 4), dim3(512), 0, stream>>>(O768, wio, ibo, P768, NG, 512, 512);
  add_ln<false><<<dim3(NG), dim3(256), 0, stream>>>(
      X768, (size_t)D_, (size_t)0, P768, X768, g3, b3);

  gemm_mfma<true ><<<dim3(3 * 16), dim3(512), 0, stream>>>(X768, w1, mb1, H768, NG, 2048, 512);
  gemm_mfma<false><<<dim3(3 * 4), dim3(512), 0, stream>>>(H768, w2, mb2, P768, NG, 512, 2048);

  // ---- fused final LN + gated combine + head ----
  final_fuse<<<dim3(BB * CC), dim3(256), 0, stream>>>(
      X768, P768, gates, g4, b4, hW, hb, out);
}

// Round 13
// 212.688 us; speedup vs baseline: 1.1995x; 1.1995x over previous
//
#include <hip/hip_runtime.h>
#include <hip/hip_bf16.h>

#define NT   49152   // Ps*B*C*L tokens
#define D_   512
#define DF_  2048
#define PS   6
#define BB   16
#define CC   8
#define LL   64
#define PREDN 96
#define NG   768     // Ps*B*C groups (tokens at l=63)

typedef unsigned short ushort_t;
using bf16x8 = __attribute__((ext_vector_type(8))) short;
using f32x4  = __attribute__((ext_vector_type(4))) float;

__device__ __forceinline__ float bf2f(unsigned short u) {
  return __uint_as_float((unsigned)u << 16);
}
__device__ __forceinline__ unsigned short f2bf(float f) {
  unsigned u = __float_as_uint(f);
  return (unsigned short)((u + 0x7fffu + ((u >> 16) & 1u)) >> 16);  // RNE
}
__device__ __forceinline__ void unp2(int x, float& a, float& b) {
  a = __uint_as_float((unsigned)x << 16);
  b = __uint_as_float((unsigned)x & 0xffff0000u);
}
__device__ __forceinline__ void gload16(const void* g, void* l) {
  __builtin_amdgcn_global_load_lds(
      (const __attribute__((address_space(1))) unsigned*)g,
      (__attribute__((address_space(3))) unsigned*)l, 16, 0, 0);
}

// ---------------------------------------------------------------------------
// bf16 MFMA GEMM, counted-vmcnt pipelined. (proven round-7 kernel, unchanged)
// C[M,N] = A[M,K] @ Bt[N,K]^T + bias, bf16 out.
// BM=256, BN=128, BK=32, 512 threads = 8 waves (4M x 2N), per-wave 64x64.
// ---------------------------------------------------------------------------
template <bool RELU>
__global__ __launch_bounds__(512, 2) void gemm_mfma(
    const ushort_t* __restrict__ A,   // [M,K] bf16 row-major
    const ushort_t* __restrict__ Bt,  // [N,K] bf16 row-major
    const float* __restrict__ bias,
    ushort_t* __restrict__ C,         // [M,N] bf16
    int M, int N, int K) {
  __shared__ __align__(16) char smem[73728];
  short* lds = (short*)smem;
  const int tid = threadIdx.x;
  const int lane = tid & 63;
  const int w = tid >> 6;       // 0..7
  const int wm = w >> 1;        // 0..3
  const int wn = w & 1;         // 0..1
  const int l15 = lane & 15, l4 = lane >> 4;

  const int nbn = N >> 7;
  const int nwg = gridDim.x;
  const int qq = nwg >> 3, rr = nwg & 7;
  const int xcd = blockIdx.x & 7, within = blockIdx.x >> 3;
  const int wg = (xcd < rr ? xcd * (qq + 1) : rr * (qq + 1) + (xcd - rr) * qq) + within;
  const int bn = (wg % nbn) << 7;
  const int bm = (wg / nbn) << 8;

  const int NKT = K >> 5;

  const int ciA0 = w * 64 + lane;
  const int ciA1 = 512 + w * 64 + lane;
  const int ciB  = w * 64 + lane;
  const int rA0 = ciA0 >> 2, rA1 = ciA1 >> 2, rB = ciB >> 2;
  const int jA0 = (ciA0 & 3) ^ ((rA0 >> 1) & 3);
  const int jA1 = (ciA1 & 3) ^ ((rA1 >> 1) & 3);
  const int jB  = (ciB  & 3) ^ ((rB  >> 1) & 3);
  const ushort_t* gA0 = A + (size_t)(bm + rA0) * K + (jA0 << 3);
  const ushort_t* gA1 = A + (size_t)(bm + rA1) * K + (jA1 << 3);
  const ushort_t* gB  = Bt + (size_t)(bn + rB) * K + (jB << 3);

  auto stage = [&](int st, int sb) {
    const int k0 = st << 5;
    gload16(gA0 + k0, smem + sb * 24576 + w * 1024);
    gload16(gA1 + k0, smem + sb * 24576 + 8192 + w * 1024);
    gload16(gB  + k0, smem + sb * 24576 + 16384 + w * 1024);
  };

  int aconst[4], bconst[4];
#pragma unroll
  for (int m = 0; m < 4; ++m) {
    int row = wm * 64 + m * 16 + l15;
    aconst[m] = row * 32 + ((l4 ^ ((row >> 1) & 3)) << 3);
  }
#pragma unroll
  for (int n = 0; n < 4; ++n) {
    int row = wn * 64 + n * 16 + l15;
    bconst[n] = 8192 + row * 32 + ((l4 ^ ((row >> 1) & 3)) << 3);
  }

  f32x4 acc[4][4] = {};

  stage(0, 0);
  stage(1, 1);

  int rb = 0, sb = 2;
  for (int kt = 0; kt < NKT; ++kt) {
    asm volatile("s_waitcnt vmcnt(3)" ::: "memory");
    __builtin_amdgcn_s_barrier();
    const short* buf = lds + rb * 12288;
    bf16x8 av[4], bv[4];
#pragma unroll
    for (int m = 0; m < 4; ++m) av[m] = *(const bf16x8*)(buf + aconst[m]);
#pragma unroll
    for (int n = 0; n < 4; ++n) bv[n] = *(const bf16x8*)(buf + bconst[n]);
    const int st = (kt + 2 < NKT) ? kt + 2 : NKT - 1;
    stage(st, sb);
    __builtin_amdgcn_s_barrier();
    __builtin_amdgcn_s_setprio(1);
#pragma unroll
    for (int m = 0; m < 4; ++m)
#pragma unroll
      for (int n = 0; n < 4; ++n)
        acc[m][n] = __builtin_amdgcn_mfma_f32_16x16x32_bf16(av[m], bv[n], acc[m][n], 0, 0, 0);
    __builtin_amdgcn_s_setprio(0);
    rb = (rb == 2) ? 0 : rb + 1;
    sb = (sb == 2) ? 0 : sb + 1;
  }

  asm volatile("s_waitcnt vmcnt(0)" ::: "memory");
  __syncthreads();

  float bc[4];
#pragma unroll
  for (int n = 0; n < 4; ++n) bc[n] = bias[bn + wn * 64 + n * 16 + l15];
  short* Cs = lds;  // [256][136] bf16
#pragma unroll
  for (int m = 0; m < 4; ++m)
#pragma unroll
    for (int n = 0; n < 4; ++n)
#pragma unroll
      for (int r2 = 0; r2 < 4; ++r2) {
        float v = acc[m][n][r2] + bc[n];
        if (RELU) v = fmaxf(v, 0.f);
        Cs[(wm * 64 + m * 16 + l4 * 4 + r2) * 136 + wn * 64 + n * 16 + l15] =
            (short)f2bf(v);
      }
  __syncthreads();
#pragma unroll
  for (int it = 0; it < 8; ++it) {
    int chunk = it * 512 + tid;
    int r = chunk >> 4;
    int c = (chunk & 15) << 3;
    int4 v = *(const int4*)(Cs + r * 136 + c);
    *(int4*)(C + (size_t)(bm + r) * N + bn + c) = v;
  }
}

// ---------------------------------------------------------------------------
// Batched transpose of 512x512 weights (blockIdx.z selects; launch z<=8).
// ---------------------------------------------------------------------------
__global__ __launch_bounds__(256) void transpose8(
    const float* s0, const float* s1, const float* s2, const float* s3,
    const float* s4, const float* s5, const float* s6, const float* s7,
    ushort_t* d0, ushort_t* d1, ushort_t* d2, ushort_t* d3,
    ushort_t* d4, ushort_t* d5, ushort_t* d6, ushort_t* d7) {
  const float* srcs[8] = {s0, s1, s2, s3, s4, s5, s6, s7};
  ushort_t* dsts[8] = {d0, d1, d2, d3, d4, d5, d6, d7};
  const float* __restrict__ W = srcs[blockIdx.z];
  ushort_t* __restrict__ Wt = dsts[blockIdx.z];
  __shared__ float tile[32][33];
  const int k0 = blockIdx.x * 32, n0 = blockIdx.y * 32;
  const int tx = threadIdx.x & 31, ty = threadIdx.x >> 5;
#pragma unroll
  for (int i = 0; i < 4; ++i)
    tile[ty + i * 8][tx] = W[(size_t)(k0 + ty + i * 8) * 512 + n0 + tx];
  __syncthreads();
#pragma unroll
  for (int i = 0; i < 4; ++i)
    Wt[(size_t)(n0 + ty + i * 8) * 512 + k0 + tx] = f2bf(tile[tx][ty + i * 8]);
}

__global__ __launch_bounds__(256) void transpose_bf16(
    const float* __restrict__ W, ushort_t* __restrict__ Wt, int K, int N) {
  __shared__ float tile[32][33];
  const int k0 = blockIdx.x * 32, n0 = blockIdx.y * 32;
  const int tx = threadIdx.x & 31, ty = threadIdx.x >> 5;
#pragma unroll
  for (int i = 0; i < 4; ++i)
    tile[ty + i * 8][tx] = W[(size_t)(k0 + ty + i * 8) * N + n0 + tx];
  __syncthreads();
#pragma unroll
  for (int i = 0; i < 4; ++i)
    Wt[(size_t)(n0 + ty + i * 8) * K + k0 + tx] = f2bf(tile[tx][ty + i * 8]);
}

// ---------------------------------------------------------------------------
// Wqk[h*512+k][kk] = (kk>>6 == h) ? bf16(cWk[k][kk]) : 0   (block-diagonal)
// grid 1024 x 256 threads; thread -> one 8-col chunk.
// ---------------------------------------------------------------------------
__global__ __launch_bounds__(256) void build_wqk(
    const float* __restrict__ cWk, ushort_t* __restrict__ Wqk) {
  int idx = blockIdx.x * 256 + threadIdx.x;   // 0..262143
  int n = idx >> 6;          // row 0..4095
  int c = (idx & 63) * 8;    // col 0..504
  int h = n >> 9, k = n & 511;
  union { unsigned short u[8]; int4 v; } pk;
  if ((c >> 6) == h) {
    float4 a = *(const float4*)(cWk + (size_t)k * 512 + c);
    float4 b = *(const float4*)(cWk + (size_t)k * 512 + c + 4);
    pk.u[0] = f2bf(a.x); pk.u[1] = f2bf(a.y); pk.u[2] = f2bf(a.z); pk.u[3] = f2bf(a.w);
    pk.u[4] = f2bf(b.x); pk.u[5] = f2bf(b.y); pk.u[6] = f2bf(b.z); pk.u[7] = f2bf(b.w);
  } else {
    pk.v = make_int4(0, 0, 0, 0);
  }
  *(int4*)(Wqk + (size_t)n * 512 + c) = pk.v;
}

// biqkv = ibq|ibk|ibv ; qz = zeros[4096]
__global__ __launch_bounds__(256) void bias_pack(
    const float* __restrict__ ibq, const float* __restrict__ ibk,
    const float* __restrict__ ibv, float* __restrict__ biqkv,
    float* __restrict__ qz) {
  int i = blockIdx.x * 256 + threadIdx.x;  // grid 22 -> 5632
  if (i < 512) biqkv[i] = ibq[i];
  else if (i < 1024) biqkv[i] = ibk[i - 512];
  else if (i < 1536) biqkv[i] = ibv[i - 1024];
  else if (i < 1536 + 4096) qz[i - 1536] = 0.f;
}

// ---------------------------------------------------------------------------
// Gather rows l=63 from f32 ex, convert to bf16.
// ---------------------------------------------------------------------------
__global__ __launch_bounds__(64) void gather_conv(
    const float* __restrict__ ex, ushort_t* __restrict__ G) {
  const int g = blockIdx.x, lane = threadIdx.x;
  const float* src = ex + ((size_t)g * 64 + 63) * 512 + lane * 8;
  float4 a = *(const float4*)src, b = *(const float4*)(src + 4);
  union { unsigned short u[8]; int4 v; } pk;
  pk.u[0] = f2bf(a.x); pk.u[1] = f2bf(a.y); pk.u[2] = f2bf(a.z); pk.u[3] = f2bf(a.w);
  pk.u[4] = f2bf(b.x); pk.u[5] = f2bf(b.y); pk.u[6] = f2bf(b.z); pk.u[7] = f2bf(b.w);
  *(int4*)(G + (size_t)g * 512 + lane * 8) = pk.v;
}

// ---------------------------------------------------------------------------
// Fused low-rank attention over L: per group g,
//   s[h,t] = 0.125 * qw[g,h,:] . x[t,:],  p = softmax_t(s),
//   y[h,:] = sum_t p[h,t] x[t,:]   -> Y[(g*8+h)][512] bf16.
// Reads ex (f32) once; QW [NG][4096] bf16 (h-major qw vectors).
// 256 threads; LDS ~79.5 KB -> 2 blocks/CU.
// ---------------------------------------------------------------------------
__global__ __launch_bounds__(256) void attn_fused(
    const float* __restrict__ ex, const ushort_t* __restrict__ QW,
    ushort_t* __restrict__ Y) {
  __shared__ short xs[64][520];
  __shared__ short qws[8][520];
  __shared__ float ss[8][72];
  __shared__ float ps[8][72];
  const int g = blockIdx.x;
  const int tid = threadIdx.x;

  {  // stage x tile: 64 rows x 512 f32 -> bf16 LDS
    const float* src = ex + (size_t)g * 64 * 512;
#pragma unroll
    for (int it = 0; it < 16; ++it) {
      int i = it * 256 + tid;          // 0..4095 chunks of 8
      int r = i >> 6, c = (i & 63) * 8;
      float4 a = *(const float4*)(src + r * 512 + c);
      float4 b = *(const float4*)(src + r * 512 + c + 4);
      union { unsigned short u[8]; int4 v; } pk;
      pk.u[0] = f2bf(a.x); pk.u[1] = f2bf(a.y); pk.u[2] = f2bf(a.z); pk.u[3] = f2bf(a.w);
      pk.u[4] = f2bf(b.x); pk.u[5] = f2bf(b.y); pk.u[6] = f2bf(b.z); pk.u[7] = f2bf(b.w);
      *(int4*)(&xs[r][c]) = pk.v;
    }
    const ushort_t* qsrc = QW + (size_t)g * 4096;
#pragma unroll
    for (int it = 0; it < 2; ++it) {
      int i = it * 256 + tid;          // 0..511 chunks of 8
      int h = i >> 6, k0 = (i & 63) * 8;
      *(int4*)(&qws[h][k0]) = *(const int4*)(qsrc + i * 8);
    }
  }
  __syncthreads();

  // scores: thread -> (h = tid&7, t = tid>>3) over 2 phases
#pragma unroll
  for (int ph = 0; ph < 2; ++ph) {
    int h = tid & 7, t = (tid >> 3) + ph * 32;
    float s0 = 0.f, s1 = 0.f, s2 = 0.f, s3 = 0.f;
    float s4 = 0.f, s5 = 0.f, s6 = 0.f, s7 = 0.f;
#pragma unroll
    for (int k8 = 0; k8 < 64; ++k8) {
      bf16x8 xv = *(const bf16x8*)(&xs[t][k8 * 8]);
      bf16x8 qv = *(const bf16x8*)(&qws[h][k8 * 8]);
      s0 += bf2f((unsigned short)xv[0]) * bf2f((unsigned short)qv[0]);
      s1 += bf2f((unsigned short)xv[1]) * bf2f((unsigned short)qv[1]);
      s2 += bf2f((unsigned short)xv[2]) * bf2f((unsigned short)qv[2]);
      s3 += bf2f((unsigned short)xv[3]) * bf2f((unsigned short)qv[3]);
      s4 += bf2f((unsigned short)xv[4]) * bf2f((unsigned short)qv[4]);
      s5 += bf2f((unsigned short)xv[5]) * bf2f((unsigned short)qv[5]);
      s6 += bf2f((unsigned short)xv[6]) * bf2f((unsigned short)qv[6]);
      s7 += bf2f((unsigned short)xv[7]) * bf2f((unsigned short)qv[7]);
    }
    ss[h][t] = (((s0 + s1) + (s2 + s3)) + ((s4 + s5) + (s6 + s7))) * 0.125f;
  }
  __syncthreads();

  // softmax per h: group of 32 threads handles one h (t and t+32)
  {
    int h = tid >> 5, t0 = tid & 31;
    float v0 = ss[h][t0], v1 = ss[h][t0 + 32];
    float mx = fmaxf(v0, v1);
#pragma unroll
    for (int o = 16; o > 0; o >>= 1) mx = fmaxf(mx, __shfl_xor(mx, o));
    float e0 = __expf(v0 - mx), e1 = __expf(v1 - mx);
    float sum = e0 + e1;
#pragma unroll
    for (int o = 16; o > 0; o >>= 1) sum += __shfl_xor(sum, o);
    float inv = 1.f / sum;
    ps[h][t0] = e0 * inv;
    ps[h][t0 + 32] = e1 * inv;
  }
  __syncthreads();

  // y[h][k0..k0+15] = sum_t p[h][t] * x[t][k0..]
  {
    int h = tid >> 5, k0 = (tid & 31) * 16;
    float acc[16] = {};
#pragma unroll
    for (int t = 0; t < 64; ++t) {
      float p = ps[h][t];
      bf16x8 x0 = *(const bf16x8*)(&xs[t][k0]);
      bf16x8 x1 = *(const bf16x8*)(&xs[t][k0 + 8]);
#pragma unroll
      for (int j = 0; j < 8; ++j) {
        acc[j]     += p * bf2f((unsigned short)x0[j]);
        acc[8 + j] += p * bf2f((unsigned short)x1[j]);
      }
    }
    union { unsigned short u[16]; int4 v[2]; } pk;
#pragma unroll
    for (int j = 0; j < 16; ++j) pk.u[j] = f2bf(acc[j]);
    ushort_t* dst = Y + ((size_t)g * 8 + h) * 512 + k0;
    *(int4*)dst = pk.v[0];
    *(int4*)(dst + 8) = pk.v[1];
  }
}

// ---------------------------------------------------------------------------
// O[g][n] = T[(g*8 + (n>>6))][n]   (diagonal head-block extract)
// ---------------------------------------------------------------------------
__global__ __launch_bounds__(64) void gather_diag(
    const ushort_t* __restrict__ T, ushort_t* __restrict__ O) {
  const int g = blockIdx.x;
  const int n0 = threadIdx.x * 8;
  const int h = n0 >> 6;
  *(int4*)(O + (size_t)g * 512 + n0) =
      *(const int4*)(T + ((size_t)g * 8 + h) * 512 + n0);
}

// ---------------------------------------------------------------------------
// Attention over context axis (S=8, dh=64) on the 768-row set.
// ---------------------------------------------------------------------------
__global__ __launch_bounds__(64) void attn_ctx(
    const ushort_t* __restrict__ QKV, ushort_t* __restrict__ O) {
  __shared__ float qs[8][72], ks[8][72], vsm[8][72], ps2[8][9];
  const int h = blockIdx.x & 7;
  const int pb = blockIdx.x >> 3;   // 0..95
  const int row0 = pb * 8;
  const int tid = threadIdx.x;
  {
    int c = tid >> 3, dc = (tid & 7) * 8;
    size_t r = (size_t)(row0 + c) * 1536 + h * 64 + dc;
    int4 qv = *(const int4*)(QKV + r);
    int4 kv = *(const int4*)(QKV + r + 512);
    int4 vv = *(const int4*)(QKV + r + 1024);
    unp2(qv.x, qs[c][dc + 0], qs[c][dc + 1]); unp2(qv.y, qs[c][dc + 2], qs[c][dc + 3]);
    unp2(qv.z, qs[c][dc + 4], qs[c][dc + 5]); unp2(qv.w, qs[c][dc + 6], qs[c][dc + 7]);
    unp2(kv.x, ks[c][dc + 0], ks[c][dc + 1]); unp2(kv.y, ks[c][dc + 2], ks[c][dc + 3]);
    unp2(kv.z, ks[c][dc + 4], ks[c][dc + 5]); unp2(kv.w, ks[c][dc + 6], ks[c][dc + 7]);
    unp2(vv.x, vsm[c][dc + 0], vsm[c][dc + 1]); unp2(vv.y, vsm[c][dc + 2], vsm[c][dc + 3]);
    unp2(vv.z, vsm[c][dc + 4], vsm[c][dc + 5]); unp2(vv.w, vsm[c][dc + 6], vsm[c][dc + 7]);
  }
  __syncthreads();
  {
    int i = tid >> 3, t = tid & 7;
    float s = 0.f;
#pragma unroll
    for (int d = 0; d < 64; ++d) s += qs[i][d] * ks[t][d];
    ps2[i][t] = s * 0.125f;
  }
  __syncthreads();
  if (tid < 8) {
    float mx = -1e30f;
#pragma unroll
    for (int t = 0; t < 8; ++t) mx = fmaxf(mx, ps2[tid][t]);
    float sum = 0.f;
#pragma unroll
    for (int t = 0; t < 8; ++t) { float e = __expf(ps2[tid][t] - mx); ps2[tid][t] = e; sum += e; }
    float inv = 1.f / sum;
#pragma unroll
    for (int t = 0; t < 8; ++t) ps2[tid][t] *= inv;
  }
  __syncthreads();
#pragma unroll
  for (int c = 0; c < 8; ++c) {
    float s = 0.f;
#pragma unroll
    for (int t = 0; t < 8; ++t) s += ps2[c][t] * vsm[t][tid];
    O[(size_t)(row0 + c) * 512 + h * 64 + tid] = f2bf(s);
  }
}

// ---------------------------------------------------------------------------
// Xout(bf16) = LN(Xin_row + T) * g + b.  Xin row at blockIdx.x*in_stride+in_base.
// ---------------------------------------------------------------------------
template <bool INF32>
__global__ __launch_bounds__(256) void add_ln(
    const void* Xin, size_t in_stride, size_t in_base,
    const ushort_t* T, ushort_t* Xout,
    const float* __restrict__ g, const float* __restrict__ b) {
  const size_t off = (size_t)blockIdx.x * D_;
  const size_t ioff = (size_t)blockIdx.x * in_stride + in_base;
  const int tid = threadIdx.x;
  float x0, x1;
  if (INF32) {
    float2 xv = ((const float2*)((const float*)Xin + ioff))[tid];
    x0 = xv.x; x1 = xv.y;
  } else {
    ushort2 xv = ((const ushort2*)((const ushort_t*)Xin + ioff))[tid];
    x0 = bf2f(xv.x); x1 = bf2f(xv.y);
  }
  ushort2 tv = ((const ushort2*)(T + off))[tid];
  x0 += bf2f(tv.x);
  x1 += bf2f(tv.y);
  float s = x0 + x1, q = x0 * x0 + x1 * x1;
#pragma unroll
  for (int o = 32; o > 0; o >>= 1) { s += __shfl_down(s, o); q += __shfl_down(q, o); }
  __shared__ float ssum[4], sqsum[4];
  if ((tid & 63) == 0) { ssum[tid >> 6] = s; sqsum[tid >> 6] = q; }
  __syncthreads();
  float S = ssum[0] + ssum[1] + ssum[2] + ssum[3];
  float Qs = sqsum[0] + sqsum[1] + sqsum[2] + sqsum[3];
  float m = S * (1.f / D_);
  float var = Qs * (1.f / D_) - m * m;
  float inv = rsqrtf(var + 1e-5f);
  float y0 = (x0 - m) * inv * g[tid * 2] + b[tid * 2];
  float y1 = (x1 - m) * inv * g[tid * 2 + 1] + b[tid * 2 + 1];
  ushort2 ov; ov.x = f2bf(y0); ov.y = f2bf(y1);
  ((ushort2*)(Xout + off))[tid] = ov;
}

// ---------------------------------------------------------------------------
// Final fusion: per (b,c): 6x LN(X+P row) -> gated sum -> head matvec.
// ---------------------------------------------------------------------------
__global__ __launch_bounds__(256) void final_fuse(
    const ushort_t* __restrict__ X, const ushort_t* __restrict__ P,
    const float* __restrict__ gates,
    const float* __restrict__ g4, const float* __restrict__ b4,
    const float* __restrict__ hW, const float* __restrict__ hb,
    float* __restrict__ out) {
  __shared__ float xr[D_];
  __shared__ float ssum[4], sqsum[4];
  const int bb = blockIdx.x >> 3, cc = blockIdx.x & 7;
  const int tid = threadIdx.x;
  const float gw0 = g4[tid * 2], gw1 = g4[tid * 2 + 1];
  const float bw0 = b4[tid * 2], bw1 = b4[tid * 2 + 1];
  float a0 = 0.f, a1 = 0.f;
#pragma unroll
  for (int p = 0; p < PS; ++p) {
    const size_t row = ((size_t)(p * BB + bb) * CC + cc) * D_;
    ushort2 xv = ((const ushort2*)(X + row))[tid];
    ushort2 tv = ((const ushort2*)(P + row))[tid];
    float x0 = bf2f(xv.x) + bf2f(tv.x);
    float x1 = bf2f(xv.y) + bf2f(tv.y);
    float s = x0 + x1, q = x0 * x0 + x1 * x1;
#pragma unroll
    for (int o = 32; o > 0; o >>= 1) { s += __shfl_down(s, o); q += __shfl_down(q, o); }
    if ((tid & 63) == 0) { ssum[tid >> 6] = s; sqsum[tid >> 6] = q; }
    __syncthreads();
    float S = ssum[0] + ssum[1] + ssum[2] + ssum[3];
    float Qs = sqsum[0] + sqsum[1] + sqsum[2] + sqsum[3];
    float m = S * (1.f / D_);
    float var = Qs * (1.f / D_) - m * m;
    float inv = rsqrtf(var + 1e-5f);
    float gate = gates[bb * PS + p];
    a0 += gate * ((x0 - m) * inv * gw0 + bw0);
    a1 += gate * ((x1 - m) * inv * gw1 + bw1);
    __syncthreads();
  }
  xr[tid * 2] = a0;
  xr[tid * 2 + 1] = a1;
  __syncthreads();
  if (tid < PREDN) {
    float s = hb[tid];
    for (int d = 0; d < D_; ++d) s += xr[d] * hW[d * PREDN + tid];
    out[((size_t)bb * PREDN + tid) * CC + cc] = s;
  }
}

// ---------------------------------------------------------------------------
extern "C" void kernel_launch(void* const* d_in, const int* in_sizes, int n_in,
                              void* d_out, int out_size, void* d_ws, size_t ws_size,
                              hipStream_t stream) {
  const float* ex    = (const float*)d_in[0];
  const float* gates = (const float*)d_in[1];
  const float* cWq = (const float*)d_in[2];  const float* cbq = (const float*)d_in[3];
  const float* cWk = (const float*)d_in[4];  const float* cbk = (const float*)d_in[5];
  const float* cWv = (const float*)d_in[6];  const float* cbv = (const float*)d_in[7];
  const float* cWo = (const float*)d_in[8];  const float* cbo = (const float*)d_in[9];
  const float* iWq = (const float*)d_in[10]; const float* ibq = (const float*)d_in[11];
  const float* iWk = (const float*)d_in[12]; const float* ibk = (const float*)d_in[13];
  const float* iWv = (const float*)d_in[14]; const float* ibv = (const float*)d_in[15];
  const float* iWo = (const float*)d_in[16]; const float* ibo = (const float*)d_in[17];
  const float* mW1 = (const float*)d_in[18]; const float* mb1 = (const float*)d_in[19];
  const float* mW2 = (const float*)d_in[20]; const float* mb2 = (const float*)d_in[21];
  const float* g1  = (const float*)d_in[22]; const float* b1  = (const float*)d_in[23];
  const float* g3  = (const float*)d_in[24]; const float* b3  = (const float*)d_in[25];
  const float* g4  = (const float*)d_in[26]; const float* b4  = (const float*)d_in[27];
  const float* hW  = (const float*)d_in[28]; const float* hb  = (const float*)d_in[29];
  float* out = (float*)d_out;

  // ---- workspace layout (shorts unless noted) ----
  ushort_t* wq    = (ushort_t*)d_ws;           // [512][512]  cWq^T
  ushort_t* wv    = wq + 262144;               // [512][512]  cWv^T
  ushort_t* wo    = wv + 262144;               // [512][512]  cWo^T
  ushort_t* wiqkv = wo + 262144;               // [1536][512]
  ushort_t* wio   = wiqkv + 786432;            // [512][512]
  ushort_t* w1    = wio + 262144;              // [2048][512]
  ushort_t* w2    = w1 + 1048576;              // [512][2048]
  ushort_t* Wqk   = w2 + 1048576;              // [4096][512] block-diag cWk
  float* biqkv = (float*)(Wqk + 2097152);      // [1536] ibq|ibk|ibv
  float* qz    = biqkv + 1536;                 // [4096] zeros
  ushort_t* G768   = (ushort_t*)(qz + 4096);   // [NG][512]
  ushort_t* Q768   = G768 + (size_t)NG * 512;  // [NG][512]
  ushort_t* QW     = Q768 + (size_t)NG * 512;  // [NG][4096]
  ushort_t* Yb     = QW + (size_t)NG * 4096;   // [NG*8][512]
  ushort_t* Tbuf   = Yb + (size_t)NG * 4096;   // [NG*8][512]
  ushort_t* O768   = Tbuf + (size_t)NG * 4096; // [NG][512]
  ushort_t* P768   = O768 + (size_t)NG * 512;  // [NG][512]
  ushort_t* X768   = P768 + (size_t)NG * 512;  // [NG][512]
  ushort_t* QKV768 = X768 + (size_t)NG * 512;  // [NG][1536]
  ushort_t* H768   = QKV768 + (size_t)NG * 1536; // [NG][2048]

  // ---- weight/bias prep ----
  transpose8<<<dim3(16, 16, 7), 256, 0, stream>>>(
      cWq, cWv, cWo, iWq, iWk, iWv, iWo, cWq,
      wq, wv, wo, wiqkv, wiqkv + 262144, wiqkv + 524288, wio, wq);
  build_wqk<<<dim3(1024), 256, 0, stream>>>(cWk, Wqk);
  transpose_bf16<<<dim3(16, 64), 256, 0, stream>>>(mW1, w1, 512, 2048);
  transpose_bf16<<<dim3(64, 16), 256, 0, stream>>>(mW2, w2, 2048, 512);
  bias_pack<<<dim3(22), 256, 0, stream>>>(ibq, ibk, ibv, biqkv, qz);

  // ---- block 1: low-rank attention over L ----
  gather_conv<<<dim3(NG), dim3(64), 0, stream>>>(ex, G768);
  gemm_mfma<false><<<dim3(3 * 4), dim3(512), 0, stream>>>(G768, wq, cbq, Q768, NG, 512, 512);
  gemm_mfma<false><<<dim3(3 * 32), dim3(512), 0, stream>>>(Q768, Wqk, qz, QW, NG, 4096, 512);
  attn_fused<<<dim3(NG), dim3(256), 0, stream>>>(ex, QW, Yb);
  gemm_mfma<false><<<dim3(24 * 4), dim3(512), 0, stream>>>(Yb, wv, cbv, Tbuf, NG * 8, 512, 512);
  gather_diag<<<dim3(NG), dim3(64), 0, stream>>>(Tbuf, O768);
  gemm_mfma<false><<<dim3(3 * 4), dim3(512), 0, stream>>>(O768, wo, cbo, P768, NG, 512, 512);
  add_ln<true><<<dim3(NG), dim3(256), 0, stream>>>(
      ex, (size_t)(LL * D_), (size_t)((LL - 1) * D_), P768, X768, g1, b1);

  // ---- block 2: attention over C ----
  gemm_mfma<false><<<dim3(3 * 12), dim3(512), 0, stream>>>(X768, wiqkv, biqkv, QKV768, NG, 1536, 512);
  attn_ctx<<<dim3(96 * 8), dim3(64), 0, stream>>>(QKV768, O768);
  gemm_mfma<false><<<dim3(3 * 4), dim3(512), 0, stream>>>(O768, wio, ibo, P768, NG, 512, 512);
  add_ln<false><<<dim3(NG), dim3(256), 0, stream>>>(
      X768, (size_t)D_, (size_t)0, P768, X768, g3, b3);

  // ---- MLP ----
  gemm_mfma<true ><<<dim3(3 * 16), dim3(512), 0, stream>>>(X768, w1, mb1, H768, NG, 2048, 512);
  gemm_mfma<false><<<dim3(3 * 4), dim3(512), 0, stream>>>(H768, w2, mb2, P768, NG, 512, 2048);

  // ---- fused final LN + gated combine + head ----
  final_fuse<<<dim3(BB * CC), dim3(256), 0, stream>>>(
      X768, P768, gates, g4, b4, hW, hb, out);
}

// Round 14
// 194.632 us; speedup vs baseline: 1.3108x; 1.0928x over previous
//
#include <hip/hip_runtime.h>
#include <hip/hip_bf16.h>

#define NT   49152   // Ps*B*C*L tokens
#define D_   512
#define DF_  2048
#define PS   6
#define BB   16
#define CC   8
#define LL   64
#define PREDN 96
#define NG   768     // Ps*B*C groups (tokens at l=63)

typedef unsigned short ushort_t;
using bf16x8 = __attribute__((ext_vector_type(8))) short;
using f32x4  = __attribute__((ext_vector_type(4))) float;

__device__ __forceinline__ float bf2f(unsigned short u) {
  return __uint_as_float((unsigned)u << 16);
}
__device__ __forceinline__ unsigned short f2bf(float f) {
  unsigned u = __float_as_uint(f);
  return (unsigned short)((u + 0x7fffu + ((u >> 16) & 1u)) >> 16);  // RNE
}
__device__ __forceinline__ void unp2(int x, float& a, float& b) {
  a = __uint_as_float((unsigned)x << 16);
  b = __uint_as_float((unsigned)x & 0xffff0000u);
}
__device__ __forceinline__ void gload16(const void* g, void* l) {
  __builtin_amdgcn_global_load_lds(
      (const __attribute__((address_space(1))) unsigned*)g,
      (__attribute__((address_space(3))) unsigned*)l, 16, 0, 0);
}

// ---------------------------------------------------------------------------
// bf16 MFMA GEMM, counted-vmcnt pipelined. (proven round-7 kernel, unchanged)
// C[M,N] = A[M,K] @ Bt[N,K]^T + bias, bf16 out.
// BM=256, BN=128, BK=32, 512 threads = 8 waves (4M x 2N), per-wave 64x64.
// ---------------------------------------------------------------------------
template <bool RELU>
__global__ __launch_bounds__(512, 2) void gemm_mfma(
    const ushort_t* __restrict__ A,   // [M,K] bf16 row-major
    const ushort_t* __restrict__ Bt,  // [N,K] bf16 row-major
    const float* __restrict__ bias,
    ushort_t* __restrict__ C,         // [M,N] bf16
    int M, int N, int K) {
  __shared__ __align__(16) char smem[73728];
  short* lds = (short*)smem;
  const int tid = threadIdx.x;
  const int lane = tid & 63;
  const int w = tid >> 6;       // 0..7
  const int wm = w >> 1;        // 0..3
  const int wn = w & 1;         // 0..1
  const int l15 = lane & 15, l4 = lane >> 4;

  const int nbn = N >> 7;
  const int nwg = gridDim.x;
  const int qq = nwg >> 3, rr = nwg & 7;
  const int xcd = blockIdx.x & 7, within = blockIdx.x >> 3;
  const int wg = (xcd < rr ? xcd * (qq + 1) : rr * (qq + 1) + (xcd - rr) * qq) + within;
  const int bn = (wg % nbn) << 7;
  const int bm = (wg / nbn) << 8;

  const int NKT = K >> 5;

  const int ciA0 = w * 64 + lane;
  const int ciA1 = 512 + w * 64 + lane;
  const int ciB  = w * 64 + lane;
  const int rA0 = ciA0 >> 2, rA1 = ciA1 >> 2, rB = ciB >> 2;
  const int jA0 = (ciA0 & 3) ^ ((rA0 >> 1) & 3);
  const int jA1 = (ciA1 & 3) ^ ((rA1 >> 1) & 3);
  const int jB  = (ciB  & 3) ^ ((rB  >> 1) & 3);
  const ushort_t* gA0 = A + (size_t)(bm + rA0) * K + (jA0 << 3);
  const ushort_t* gA1 = A + (size_t)(bm + rA1) * K + (jA1 << 3);
  const ushort_t* gB  = Bt + (size_t)(bn + rB) * K + (jB << 3);

  auto stage = [&](int st, int sb) {
    const int k0 = st << 5;
    gload16(gA0 + k0, smem + sb * 24576 + w * 1024);
    gload16(gA1 + k0, smem + sb * 24576 + 8192 + w * 1024);
    gload16(gB  + k0, smem + sb * 24576 + 16384 + w * 1024);
  };

  int aconst[4], bconst[4];
#pragma unroll
  for (int m = 0; m < 4; ++m) {
    int row = wm * 64 + m * 16 + l15;
    aconst[m] = row * 32 + ((l4 ^ ((row >> 1) & 3)) << 3);
  }
#pragma unroll
  for (int n = 0; n < 4; ++n) {
    int row = wn * 64 + n * 16 + l15;
    bconst[n] = 8192 + row * 32 + ((l4 ^ ((row >> 1) & 3)) << 3);
  }

  f32x4 acc[4][4] = {};

  stage(0, 0);
  stage(1, 1);

  int rb = 0, sb = 2;
  for (int kt = 0; kt < NKT; ++kt) {
    asm volatile("s_waitcnt vmcnt(3)" ::: "memory");
    __builtin_amdgcn_s_barrier();
    const short* buf = lds + rb * 12288;
    bf16x8 av[4], bv[4];
#pragma unroll
    for (int m = 0; m < 4; ++m) av[m] = *(const bf16x8*)(buf + aconst[m]);
#pragma unroll
    for (int n = 0; n < 4; ++n) bv[n] = *(const bf16x8*)(buf + bconst[n]);
    const int st = (kt + 2 < NKT) ? kt + 2 : NKT - 1;
    stage(st, sb);
    __builtin_amdgcn_s_barrier();
    __builtin_amdgcn_s_setprio(1);
#pragma unroll
    for (int m = 0; m < 4; ++m)
#pragma unroll
      for (int n = 0; n < 4; ++n)
        acc[m][n] = __builtin_amdgcn_mfma_f32_16x16x32_bf16(av[m], bv[n], acc[m][n], 0, 0, 0);
    __builtin_amdgcn_s_setprio(0);
    rb = (rb == 2) ? 0 : rb + 1;
    sb = (sb == 2) ? 0 : sb + 1;
  }

  asm volatile("s_waitcnt vmcnt(0)" ::: "memory");
  __syncthreads();

  float bc[4];
#pragma unroll
  for (int n = 0; n < 4; ++n) bc[n] = bias[bn + wn * 64 + n * 16 + l15];
  short* Cs = lds;  // [256][136] bf16
#pragma unroll
  for (int m = 0; m < 4; ++m)
#pragma unroll
    for (int n = 0; n < 4; ++n)
#pragma unroll
      for (int r2 = 0; r2 < 4; ++r2) {
        float v = acc[m][n][r2] + bc[n];
        if (RELU) v = fmaxf(v, 0.f);
        Cs[(wm * 64 + m * 16 + l4 * 4 + r2) * 136 + wn * 64 + n * 16 + l15] =
            (short)f2bf(v);
      }
  __syncthreads();
#pragma unroll
  for (int it = 0; it < 8; ++it) {
    int chunk = it * 512 + tid;
    int r = chunk >> 4;
    int c = (chunk & 15) << 3;
    int4 v = *(const int4*)(Cs + r * 136 + c);
    *(int4*)(C + (size_t)(bm + r) * N + bn + c) = v;
  }
}

// ---------------------------------------------------------------------------
// Batched transpose of 512x512 weights (blockIdx.z selects; launch z<=8).
// ---------------------------------------------------------------------------
__global__ __launch_bounds__(256) void transpose8(
    const float* s0, const float* s1, const float* s2, const float* s3,
    const float* s4, const float* s5, const float* s6, const float* s7,
    ushort_t* d0, ushort_t* d1, ushort_t* d2, ushort_t* d3,
    ushort_t* d4, ushort_t* d5, ushort_t* d6, ushort_t* d7) {
  const float* srcs[8] = {s0, s1, s2, s3, s4, s5, s6, s7};
  ushort_t* dsts[8] = {d0, d1, d2, d3, d4, d5, d6, d7};
  const float* __restrict__ W = srcs[blockIdx.z];
  ushort_t* __restrict__ Wt = dsts[blockIdx.z];
  __shared__ float tile[32][33];
  const int k0 = blockIdx.x * 32, n0 = blockIdx.y * 32;
  const int tx = threadIdx.x & 31, ty = threadIdx.x >> 5;
#pragma unroll
  for (int i = 0; i < 4; ++i)
    tile[ty + i * 8][tx] = W[(size_t)(k0 + ty + i * 8) * 512 + n0 + tx];
  __syncthreads();
#pragma unroll
  for (int i = 0; i < 4; ++i)
    Wt[(size_t)(n0 + ty + i * 8) * 512 + k0 + tx] = f2bf(tile[tx][ty + i * 8]);
}

__global__ __launch_bounds__(256) void transpose_bf16(
    const float* __restrict__ W, ushort_t* __restrict__ Wt, int K, int N) {
  __shared__ float tile[32][33];
  const int k0 = blockIdx.x * 32, n0 = blockIdx.y * 32;
  const int tx = threadIdx.x & 31, ty = threadIdx.x >> 5;
#pragma unroll
  for (int i = 0; i < 4; ++i)
    tile[ty + i * 8][tx] = W[(size_t)(k0 + ty + i * 8) * N + n0 + tx];
  __syncthreads();
#pragma unroll
  for (int i = 0; i < 4; ++i)
    Wt[(size_t)(n0 + ty + i * 8) * K + k0 + tx] = f2bf(tile[tx][ty + i * 8]);
}

// ---------------------------------------------------------------------------
// Wqk[h*512+k][kk] = (kk>>6 == h) ? bf16(cWk[k][kk]) : 0   (block-diagonal)
// ---------------------------------------------------------------------------
__global__ __launch_bounds__(256) void build_wqk(
    const float* __restrict__ cWk, ushort_t* __restrict__ Wqk) {
  int idx = blockIdx.x * 256 + threadIdx.x;   // 0..262143
  int n = idx >> 6;          // row 0..4095
  int c = (idx & 63) * 8;    // col 0..504
  int h = n >> 9, k = n & 511;
  union { unsigned short u[8]; int4 v; } pk;
  if ((c >> 6) == h) {
    float4 a = *(const float4*)(cWk + (size_t)k * 512 + c);
    float4 b = *(const float4*)(cWk + (size_t)k * 512 + c + 4);
    pk.u[0] = f2bf(a.x); pk.u[1] = f2bf(a.y); pk.u[2] = f2bf(a.z); pk.u[3] = f2bf(a.w);
    pk.u[4] = f2bf(b.x); pk.u[5] = f2bf(b.y); pk.u[6] = f2bf(b.z); pk.u[7] = f2bf(b.w);
  } else {
    pk.v = make_int4(0, 0, 0, 0);
  }
  *(int4*)(Wqk + (size_t)n * 512 + c) = pk.v;
}

// biqkv = ibq|ibk|ibv ; qz = zeros[4096]
__global__ __launch_bounds__(256) void bias_pack(
    const float* __restrict__ ibq, const float* __restrict__ ibk,
    const float* __restrict__ ibv, float* __restrict__ biqkv,
    float* __restrict__ qz) {
  int i = blockIdx.x * 256 + threadIdx.x;  // grid 22 -> 5632
  if (i < 512) biqkv[i] = ibq[i];
  else if (i < 1024) biqkv[i] = ibk[i - 512];
  else if (i < 1536) biqkv[i] = ibv[i - 1024];
  else if (i < 1536 + 4096) qz[i - 1536] = 0.f;
}

// ---------------------------------------------------------------------------
// Gather rows l=63 from f32 ex, convert to bf16.
// ---------------------------------------------------------------------------
__global__ __launch_bounds__(64) void gather_conv(
    const float* __restrict__ ex, ushort_t* __restrict__ G) {
  const int g = blockIdx.x, lane = threadIdx.x;
  const float* src = ex + ((size_t)g * 64 + 63) * 512 + lane * 8;
  float4 a = *(const float4*)src, b = *(const float4*)(src + 4);
  union { unsigned short u[8]; int4 v; } pk;
  pk.u[0] = f2bf(a.x); pk.u[1] = f2bf(a.y); pk.u[2] = f2bf(a.z); pk.u[3] = f2bf(a.w);
  pk.u[4] = f2bf(b.x); pk.u[5] = f2bf(b.y); pk.u[6] = f2bf(b.z); pk.u[7] = f2bf(b.w);
  *(int4*)(G + (size_t)g * 512 + lane * 8) = pk.v;
}

// ---------------------------------------------------------------------------
// Fused low-rank attention over L (round-14: 512 threads, MFMA scores).
//   S^T[h][t] = 0.125 * qw[g,h,:] . x[t,:]   via mfma (waves 0-3),
//   p = softmax_t, y[h,:] = sum_t p[h,t] x[t,:] (wave h owns head h).
// LDS ~79.4 KB -> 2 blocks/CU x 8 waves = 16 waves/CU.
// ---------------------------------------------------------------------------
__global__ __launch_bounds__(512, 4) void attn_fused(
    const float* __restrict__ ex, const ushort_t* __restrict__ QW,
    ushort_t* __restrict__ Y) {
  __shared__ short xs[64][520];
  __shared__ short qws[8][520];
  __shared__ float ss[8][72];
  __shared__ float ps[8][72];
  const int g = blockIdx.x;
  const int tid = threadIdx.x;
  const int lane = tid & 63;
  const int w = tid >> 6;

  {  // stage x tile: 64 rows x 512 f32 -> bf16 LDS (8 iters/thread)
    const float* src = ex + (size_t)g * 64 * 512;
#pragma unroll
    for (int it = 0; it < 8; ++it) {
      int i = it * 512 + tid;          // 0..4095 chunks of 8
      int r = i >> 6, c = (i & 63) * 8;
      float4 a = *(const float4*)(src + r * 512 + c);
      float4 b = *(const float4*)(src + r * 512 + c + 4);
      union { unsigned short u[8]; int4 v; } pk;
      pk.u[0] = f2bf(a.x); pk.u[1] = f2bf(a.y); pk.u[2] = f2bf(a.z); pk.u[3] = f2bf(a.w);
      pk.u[4] = f2bf(b.x); pk.u[5] = f2bf(b.y); pk.u[6] = f2bf(b.z); pk.u[7] = f2bf(b.w);
      *(int4*)(&xs[r][c]) = pk.v;
    }
    // qw: 512 chunks of 8 -> one per thread
    int h = tid >> 6, k0 = (tid & 63) * 8;
    *(int4*)(&qws[h][k0]) = *(const int4*)(QW + (size_t)g * 4096 + tid * 8);
  }
  __syncthreads();

  // scores via MFMA: S^T[h][t] ; wave w owns t-tile [16w, 16w+16)
  if (w < 4) {
    f32x4 acc = {0.f, 0.f, 0.f, 0.f};
    const int arow = lane & 7;          // qw row (rows 8-15 aliased, discarded)
    const int koff = (lane >> 4) * 8;
    const short* xrow = &xs[16 * w + (lane & 15)][0];
#pragma unroll
    for (int ks = 0; ks < 16; ++ks) {
      bf16x8 av = *(const bf16x8*)(&qws[arow][ks * 32 + koff]);
      bf16x8 bv = *(const bf16x8*)(xrow + ks * 32 + koff);
      acc = __builtin_amdgcn_mfma_f32_16x16x32_bf16(av, bv, acc, 0, 0, 0);
    }
    int t = 16 * w + (lane & 15);
    int hbase = (lane >> 4) * 4;
#pragma unroll
    for (int r = 0; r < 4; ++r) {
      int h = hbase + r;
      if (h < 8) ss[h][t] = acc[r] * 0.125f;
    }
  }
  __syncthreads();

  // softmax per h: 32 threads per h (threads 0..255)
  if (tid < 256) {
    int h = tid >> 5, t0 = tid & 31;
    float v0 = ss[h][t0], v1 = ss[h][t0 + 32];
    float mx = fmaxf(v0, v1);
#pragma unroll
    for (int o = 16; o > 0; o >>= 1) mx = fmaxf(mx, __shfl_xor(mx, o));
    float e0 = __expf(v0 - mx), e1 = __expf(v1 - mx);
    float sum = e0 + e1;
#pragma unroll
    for (int o = 16; o > 0; o >>= 1) sum += __shfl_xor(sum, o);
    float inv = 1.f / sum;
    ps[h][t0] = e0 * inv;
    ps[h][t0 + 32] = e1 * inv;
  }
  __syncthreads();

  // y[h][k0..k0+7] = sum_t p[h][t] * x[t][k0..] ; wave w = head h
  {
    const int k0 = lane * 8;
    float acc[8] = {};
#pragma unroll
    for (int t = 0; t < 64; ++t) {
      float p = ps[w][t];
      bf16x8 xv = *(const bf16x8*)(&xs[t][k0]);
#pragma unroll
      for (int j = 0; j < 8; ++j) acc[j] += p * bf2f((unsigned short)xv[j]);
    }
    union { unsigned short u[8]; int4 v; } pk;
#pragma unroll
    for (int j = 0; j < 8; ++j) pk.u[j] = f2bf(acc[j]);
    *(int4*)(Y + ((size_t)g * 8 + w) * 512 + k0) = pk.v;
  }
}

// ---------------------------------------------------------------------------
// O[g][n] = T[(g*8 + (n>>6))][n]   (diagonal head-block extract)
// ---------------------------------------------------------------------------
__global__ __launch_bounds__(64) void gather_diag(
    const ushort_t* __restrict__ T, ushort_t* __restrict__ O) {
  const int g = blockIdx.x;
  const int n0 = threadIdx.x * 8;
  const int h = n0 >> 6;
  *(int4*)(O + (size_t)g * 512 + n0) =
      *(const int4*)(T + ((size_t)g * 8 + h) * 512 + n0);
}

// ---------------------------------------------------------------------------
// Attention over context axis (S=8, dh=64) on the 768-row set.
// ---------------------------------------------------------------------------
__global__ __launch_bounds__(64) void attn_ctx(
    const ushort_t* __restrict__ QKV, ushort_t* __restrict__ O) {
  __shared__ float qs[8][72], ks[8][72], vsm[8][72], ps2[8][9];
  const int h = blockIdx.x & 7;
  const int pb = blockIdx.x >> 3;   // 0..95
  const int row0 = pb * 8;
  const int tid = threadIdx.x;
  {
    int c = tid >> 3, dc = (tid & 7) * 8;
    size_t r = (size_t)(row0 + c) * 1536 + h * 64 + dc;
    int4 qv = *(const int4*)(QKV + r);
    int4 kv = *(const int4*)(QKV + r + 512);
    int4 vv = *(const int4*)(QKV + r + 1024);
    unp2(qv.x, qs[c][dc + 0], qs[c][dc + 1]); unp2(qv.y, qs[c][dc + 2], qs[c][dc + 3]);
    unp2(qv.z, qs[c][dc + 4], qs[c][dc + 5]); unp2(qv.w, qs[c][dc + 6], qs[c][dc + 7]);
    unp2(kv.x, ks[c][dc + 0], ks[c][dc + 1]); unp2(kv.y, ks[c][dc + 2], ks[c][dc + 3]);
    unp2(kv.z, ks[c][dc + 4], ks[c][dc + 5]); unp2(kv.w, ks[c][dc + 6], ks[c][dc + 7]);
    unp2(vv.x, vsm[c][dc + 0], vsm[c][dc + 1]); unp2(vv.y, vsm[c][dc + 2], vsm[c][dc + 3]);
    unp2(vv.z, vsm[c][dc + 4], vsm[c][dc + 5]); unp2(vv.w, vsm[c][dc + 6], vsm[c][dc + 7]);
  }
  __syncthreads();
  {
    int i = tid >> 3, t = tid & 7;
    float s = 0.f;
#pragma unroll
    for (int d = 0; d < 64; ++d) s += qs[i][d] * ks[t][d];
    ps2[i][t] = s * 0.125f;
  }
  __syncthreads();
  if (tid < 8) {
    float mx = -1e30f;
#pragma unroll
    for (int t = 0; t < 8; ++t) mx = fmaxf(mx, ps2[tid][t]);
    float sum = 0.f;
#pragma unroll
    for (int t = 0; t < 8; ++t) { float e = __expf(ps2[tid][t] - mx); ps2[tid][t] = e; sum += e; }
    float inv = 1.f / sum;
#pragma unroll
    for (int t = 0; t < 8; ++t) ps2[tid][t] *= inv;
  }
  __syncthreads();
#pragma unroll
  for (int c = 0; c < 8; ++c) {
    float s = 0.f;
#pragma unroll
    for (int t = 0; t < 8; ++t) s += ps2[c][t] * vsm[t][tid];
    O[(size_t)(row0 + c) * 512 + h * 64 + tid] = f2bf(s);
  }
}

// ---------------------------------------------------------------------------
// Xout(bf16) = LN(Xin_row + T) * g + b.  Xin row at blockIdx.x*in_stride+in_base.
// ---------------------------------------------------------------------------
template <bool INF32>
__global__ __launch_bounds__(256) void add_ln(
    const void* Xin, size_t in_stride, size_t in_base,
    const ushort_t* T, ushort_t* Xout,
    const float* __restrict__ g, const float* __restrict__ b) {
  const size_t off = (size_t)blockIdx.x * D_;
  const size_t ioff = (size_t)blockIdx.x * in_stride + in_base;
  const int tid = threadIdx.x;
  float x0, x1;
  if (INF32) {
    float2 xv = ((const float2*)((const float*)Xin + ioff))[tid];
    x0 = xv.x; x1 = xv.y;
  } else {
    ushort2 xv = ((const ushort2*)((const ushort_t*)Xin + ioff))[tid];
    x0 = bf2f(xv.x); x1 = bf2f(xv.y);
  }
  ushort2 tv = ((const ushort2*)(T + off))[tid];
  x0 += bf2f(tv.x);
  x1 += bf2f(tv.y);
  float s = x0 + x1, q = x0 * x0 + x1 * x1;
#pragma unroll
  for (int o = 32; o > 0; o >>= 1) { s += __shfl_down(s, o); q += __shfl_down(q, o); }
  __shared__ float ssum[4], sqsum[4];
  if ((tid & 63) == 0) { ssum[tid >> 6] = s; sqsum[tid >> 6] = q; }
  __syncthreads();
  float S = ssum[0] + ssum[1] + ssum[2] + ssum[3];
  float Qs = sqsum[0] + sqsum[1] + sqsum[2] + sqsum[3];
  float m = S * (1.f / D_);
  float var = Qs * (1.f / D_) - m * m;
  float inv = rsqrtf(var + 1e-5f);
  float y0 = (x0 - m) * inv * g[tid * 2] + b[tid * 2];
  float y1 = (x1 - m) * inv * g[tid * 2 + 1] + b[tid * 2 + 1];
  ushort2 ov; ov.x = f2bf(y0); ov.y = f2bf(y1);
  ((ushort2*)(Xout + off))[tid] = ov;
}

// ---------------------------------------------------------------------------
// Final fusion: per (b,c): 6x LN(X+P row) -> gated sum -> head matvec.
// ---------------------------------------------------------------------------
__global__ __launch_bounds__(256) void final_fuse(
    const ushort_t* __restrict__ X, const ushort_t* __restrict__ P,
    const float* __restrict__ gates,
    const float* __restrict__ g4, const float* __restrict__ b4,
    const float* __restrict__ hW, const float* __restrict__ hb,
    float* __restrict__ out) {
  __shared__ float xr[D_];
  __shared__ float ssum[4], sqsum[4];
  const int bb = blockIdx.x >> 3, cc = blockIdx.x & 7;
  const int tid = threadIdx.x;
  const float gw0 = g4[tid * 2], gw1 = g4[tid * 2 + 1];
  const float bw0 = b4[tid * 2], bw1 = b4[tid * 2 + 1];
  float a0 = 0.f, a1 = 0.f;
#pragma unroll
  for (int p = 0; p < PS; ++p) {
    const size_t row = ((size_t)(p * BB + bb) * CC + cc) * D_;
    ushort2 xv = ((const ushort2*)(X + row))[tid];
    ushort2 tv = ((const ushort2*)(P + row))[tid];
    float x0 = bf2f(xv.x) + bf2f(tv.x);
    float x1 = bf2f(xv.y) + bf2f(tv.y);
    float s = x0 + x1, q = x0 * x0 + x1 * x1;
#pragma unroll
    for (int o = 32; o > 0; o >>= 1) { s += __shfl_down(s, o); q += __shfl_down(q, o); }
    if ((tid & 63) == 0) { ssum[tid >> 6] = s; sqsum[tid >> 6] = q; }
    __syncthreads();
    float S = ssum[0] + ssum[1] + ssum[2] + ssum[3];
    float Qs = sqsum[0] + sqsum[1] + sqsum[2] + sqsum[3];
    float m = S * (1.f / D_);
    float var = Qs * (1.f / D_) - m * m;
    float inv = rsqrtf(var + 1e-5f);
    float gate = gates[bb * PS + p];
    a0 += gate * ((x0 - m) * inv * gw0 + bw0);
    a1 += gate * ((x1 - m) * inv * gw1 + bw1);
    __syncthreads();
  }
  xr[tid * 2] = a0;
  xr[tid * 2 + 1] = a1;
  __syncthreads();
  if (tid < PREDN) {
    float s = hb[tid];
    for (int d = 0; d < D_; ++d) s += xr[d] * hW[d * PREDN + tid];
    out[((size_t)bb * PREDN + tid) * CC + cc] = s;
  }
}

// ---------------------------------------------------------------------------
extern "C" void kernel_launch(void* const* d_in, const int* in_sizes, int n_in,
                              void* d_out, int out_size, void* d_ws, size_t ws_size,
                              hipStream_t stream) {
  const float* ex    = (const float*)d_in[0];
  const float* gates = (const float*)d_in[1];
  const float* cWq = (const float*)d_in[2];  const float* cbq = (const float*)d_in[3];
  const float* cWk = (const float*)d_in[4];  const float* cbk = (const float*)d_in[5];
  const float* cWv = (const float*)d_in[6];  const float* cbv = (const float*)d_in[7];
  const float* cWo = (const float*)d_in[8];  const float* cbo = (const float*)d_in[9];
  const float* iWq = (const float*)d_in[10]; const float* ibq = (const float*)d_in[11];
  const float* iWk = (const float*)d_in[12]; const float* ibk = (const float*)d_in[13];
  const float* iWv = (const float*)d_in[14]; const float* ibv = (const float*)d_in[15];
  const float* iWo = (const float*)d_in[16]; const float* ibo = (const float*)d_in[17];
  const float* mW1 = (const float*)d_in[18]; const float* mb1 = (const float*)d_in[19];
  const float* mW2 = (const float*)d_in[20]; const float* mb2 = (const float*)d_in[21];
  const float* g1  = (const float*)d_in[22]; const float* b1  = (const float*)d_in[23];
  const float* g3  = (const float*)d_in[24]; const float* b3  = (const float*)d_in[25];
  const float* g4  = (const float*)d_in[26]; const float* b4  = (const float*)d_in[27];
  const float* hW  = (const float*)d_in[28]; const float* hb  = (const float*)d_in[29];
  float* out = (float*)d_out;

  // ---- workspace layout (shorts unless noted) ----
  ushort_t* wq    = (ushort_t*)d_ws;           // [512][512]  cWq^T
  ushort_t* wv    = wq + 262144;               // [512][512]  cWv^T
  ushort_t* wo    = wv + 262144;               // [512][512]  cWo^T
  ushort_t* wiqkv = wo + 262144;               // [1536][512]
  ushort_t* wio   = wiqkv + 786432;            // [512][512]
  ushort_t* w1    = wio + 262144;              // [2048][512]
  ushort_t* w2    = w1 + 1048576;              // [512][2048]
  ushort_t* Wqk   = w2 + 1048576;              // [4096][512] block-diag cWk
  float* biqkv = (float*)(Wqk + 2097152);      // [1536] ibq|ibk|ibv
  float* qz    = biqkv + 1536;                 // [4096] zeros
  ushort_t* G768   = (ushort_t*)(qz + 4096);   // [NG][512]
  ushort_t* Q768   = G768 + (size_t)NG * 512;  // [NG][512]
  ushort_t* QW     = Q768 + (size_t)NG * 512;  // [NG][4096]
  ushort_t* Yb     = QW + (size_t)NG * 4096;   // [NG*8][512]
  ushort_t* Tbuf   = Yb + (size_t)NG * 4096;   // [NG*8][512]
  ushort_t* O768   = Tbuf + (size_t)NG * 4096; // [NG][512]
  ushort_t* P768   = O768 + (size_t)NG * 512;  // [NG][512]
  ushort_t* X768   = P768 + (size_t)NG * 512;  // [NG][512]
  ushort_t* QKV768 = X768 + (size_t)NG * 512;  // [NG][1536]
  ushort_t* H768   = QKV768 + (size_t)NG * 1536; // [NG][2048]

  // ---- weight/bias prep ----
  transpose8<<<dim3(16, 16, 7), 256, 0, stream>>>(
      cWq, cWv, cWo, iWq, iWk, iWv, iWo, cWq,
      wq, wv, wo, wiqkv, wiqkv + 262144, wiqkv + 524288, wio, wq);
  build_wqk<<<dim3(1024), 256, 0, stream>>>(cWk, Wqk);
  transpose_bf16<<<dim3(16, 64), 256, 0, stream>>>(mW1, w1, 512, 2048);
  transpose_bf16<<<dim3(64, 16), 256, 0, stream>>>(mW2, w2, 2048, 512);
  bias_pack<<<dim3(22), 256, 0, stream>>>(ibq, ibk, ibv, biqkv, qz);

  // ---- block 1: low-rank attention over L ----
  gather_conv<<<dim3(NG), dim3(64), 0, stream>>>(ex, G768);
  gemm_mfma<false><<<dim3(3 * 4), dim3(512), 0, stream>>>(G768, wq, cbq, Q768, NG, 512, 512);
  gemm_mfma<false><<<dim3(3 * 32), dim3(512), 0, stream>>>(Q768, Wqk, qz, QW, NG, 4096, 512);
  attn_fused<<<dim3(NG), dim3(512), 0, stream>>>(ex, QW, Yb);
  gemm_mfma<false><<<dim3(24 * 4), dim3(512), 0, stream>>>(Yb, wv, cbv, Tbuf, NG * 8, 512, 512);
  gather_diag<<<dim3(NG), dim3(64), 0, stream>>>(Tbuf, O768);
  gemm_mfma<false><<<dim3(3 * 4), dim3(512), 0, stream>>>(O768, wo, cbo, P768, NG, 512, 512);
  add_ln<true><<<dim3(NG), dim3(256), 0, stream>>>(
      ex, (size_t)(LL * D_), (size_t)((LL - 1) * D_), P768, X768, g1, b1);

  // ---- block 2: attention over C ----
  gemm_mfma<false><<<dim3(3 * 12), dim3(512), 0, stream>>>(X768, wiqkv, biqkv, QKV768, NG, 1536, 512);
  attn_ctx<<<dim3(96 * 8), dim3(64), 0, stream>>>(QKV768, O768);
  gemm_mfma<false><<<dim3(3 * 4), dim3(512), 0, stream>>>(O768, wio, ibo, P768, NG, 512, 512);
  add_ln<false><<<dim3(NG), dim3(256), 0, stream>>>(
      X768, (size_t)D_, (size_t)0, P768, X768, g3, b3);

  // ---- MLP ----
  gemm_mfma<true ><<<dim3(3 * 16), dim3(512), 0, stream>>>(X768, w1, mb1, H768, NG, 2048, 512);
  gemm_mfma<false><<<dim3(3 * 4), dim3(512), 0, stream>>>(H768, w2, mb2, P768, NG, 512, 2048);

  // ---- fused final LN + gated combine + head ----
  final_fuse<<<dim3(BB * CC), dim3(256), 0, stream>>>(
      X768, P768, gates, g4, b4, hW, hb, out);
}

// Round 15
// 181.921 us; speedup vs baseline: 1.4024x; 1.0699x over previous
//
#include <hip/hip_runtime.h>
#include <hip/hip_bf16.h>

#define NT   49152   // Ps*B*C*L tokens
#define D_   512
#define DF_  2048
#define PS   6
#define BB   16
#define CC   8
#define LL   64
#define PREDN 96
#define NG   768     // Ps*B*C groups (tokens at l=63)

typedef unsigned short ushort_t;
using bf16x8 = __attribute__((ext_vector_type(8))) short;
using f32x4  = __attribute__((ext_vector_type(4))) float;

__device__ __forceinline__ float bf2f(unsigned short u) {
  return __uint_as_float((unsigned)u << 16);
}
__device__ __forceinline__ unsigned short f2bf(float f) {
  unsigned u = __float_as_uint(f);
  return (unsigned short)((u + 0x7fffu + ((u >> 16) & 1u)) >> 16);  // RNE
}
__device__ __forceinline__ void unp2(int x, float& a, float& b) {
  a = __uint_as_float((unsigned)x << 16);
  b = __uint_as_float((unsigned)x & 0xffff0000u);
}
__device__ __forceinline__ void gload16(const void* g, void* l) {
  __builtin_amdgcn_global_load_lds(
      (const __attribute__((address_space(1))) unsigned*)g,
      (__attribute__((address_space(3))) unsigned*)l, 16, 0, 0);
}

// ---------------------------------------------------------------------------
// bf16 MFMA GEMM, counted-vmcnt pipelined (proven round-7 kernel).
// C[M,N] = A[M,K] @ Bt[N,K]^T + bias, bf16 out.
// BM=256, BN=128, BK=32, 512 threads = 8 waves (4M x 2N), per-wave 64x64.
// DIAGA (requires K==512): A[r][k] = Araw[(r*8 + (k>>6))*512 + k] — reads the
// diagonal head-blocks of a [M*8][512] tensor directly (per-lane global src).
// ---------------------------------------------------------------------------
template <bool RELU, bool DIAGA>
__global__ __launch_bounds__(512, 2) void gemm_mfma(
    const ushort_t* __restrict__ A,   // [M,K] bf16 (or [M*8][512] when DIAGA)
    const ushort_t* __restrict__ Bt,  // [N,K] bf16 row-major
    const float* __restrict__ bias,
    ushort_t* __restrict__ C,         // [M,N] bf16
    int M, int N, int K) {
  __shared__ __align__(16) char smem[73728];
  short* lds = (short*)smem;
  const int tid = threadIdx.x;
  const int lane = tid & 63;
  const int w = tid >> 6;       // 0..7
  const int wm = w >> 1;        // 0..3
  const int wn = w & 1;         // 0..1
  const int l15 = lane & 15, l4 = lane >> 4;

  const int nbn = N >> 7;
  const int nwg = gridDim.x;
  const int qq = nwg >> 3, rr = nwg & 7;
  const int xcd = blockIdx.x & 7, within = blockIdx.x >> 3;
  const int wg = (xcd < rr ? xcd * (qq + 1) : rr * (qq + 1) + (xcd - rr) * qq) + within;
  const int bn = (wg % nbn) << 7;
  const int bm = (wg / nbn) << 8;

  const int NKT = K >> 5;

  const int ciA0 = w * 64 + lane;
  const int ciA1 = 512 + w * 64 + lane;
  const int ciB  = w * 64 + lane;
  const int rA0 = ciA0 >> 2, rA1 = ciA1 >> 2, rB = ciB >> 2;
  const int jA0 = (ciA0 & 3) ^ ((rA0 >> 1) & 3);
  const int jA1 = (ciA1 & 3) ^ ((rA1 >> 1) & 3);
  const int jB  = (ciB  & 3) ^ ((rB  >> 1) & 3);
  const ushort_t* gA0 = A + (size_t)(bm + rA0) * K + (jA0 << 3);
  const ushort_t* gA1 = A + (size_t)(bm + rA1) * K + (jA1 << 3);
  const ushort_t* gB  = Bt + (size_t)(bn + rB) * K + (jB << 3);

  auto stage = [&](int st, int sb) {
    const int k0 = st << 5;
    if (DIAGA) {
      const int kk0 = k0 + (jA0 << 3);
      const int kk1 = k0 + (jA1 << 3);
      gload16(A + ((size_t)(bm + rA0) * 8 + (kk0 >> 6)) * 512 + kk0,
              smem + sb * 24576 + w * 1024);
      gload16(A + ((size_t)(bm + rA1) * 8 + (kk1 >> 6)) * 512 + kk1,
              smem + sb * 24576 + 8192 + w * 1024);
    } else {
      gload16(gA0 + k0, smem + sb * 24576 + w * 1024);
      gload16(gA1 + k0, smem + sb * 24576 + 8192 + w * 1024);
    }
    gload16(gB + k0, smem + sb * 24576 + 16384 + w * 1024);
  };

  int aconst[4], bconst[4];
#pragma unroll
  for (int m = 0; m < 4; ++m) {
    int row = wm * 64 + m * 16 + l15;
    aconst[m] = row * 32 + ((l4 ^ ((row >> 1) & 3)) << 3);
  }
#pragma unroll
  for (int n = 0; n < 4; ++n) {
    int row = wn * 64 + n * 16 + l15;
    bconst[n] = 8192 + row * 32 + ((l4 ^ ((row >> 1) & 3)) << 3);
  }

  f32x4 acc[4][4] = {};

  stage(0, 0);
  stage(1, 1);

  int rb = 0, sb = 2;
  for (int kt = 0; kt < NKT; ++kt) {
    asm volatile("s_waitcnt vmcnt(3)" ::: "memory");
    __builtin_amdgcn_s_barrier();
    const short* buf = lds + rb * 12288;
    bf16x8 av[4], bv[4];
#pragma unroll
    for (int m = 0; m < 4; ++m) av[m] = *(const bf16x8*)(buf + aconst[m]);
#pragma unroll
    for (int n = 0; n < 4; ++n) bv[n] = *(const bf16x8*)(buf + bconst[n]);
    const int st = (kt + 2 < NKT) ? kt + 2 : NKT - 1;
    stage(st, sb);
    __builtin_amdgcn_s_barrier();
    __builtin_amdgcn_s_setprio(1);
#pragma unroll
    for (int m = 0; m < 4; ++m)
#pragma unroll
      for (int n = 0; n < 4; ++n)
        acc[m][n] = __builtin_amdgcn_mfma_f32_16x16x32_bf16(av[m], bv[n], acc[m][n], 0, 0, 0);
    __builtin_amdgcn_s_setprio(0);
    rb = (rb == 2) ? 0 : rb + 1;
    sb = (sb == 2) ? 0 : sb + 1;
  }

  asm volatile("s_waitcnt vmcnt(0)" ::: "memory");
  __syncthreads();

  float bc[4];
#pragma unroll
  for (int n = 0; n < 4; ++n) bc[n] = bias[bn + wn * 64 + n * 16 + l15];
  short* Cs = lds;  // [256][136] bf16
#pragma unroll
  for (int m = 0; m < 4; ++m)
#pragma unroll
    for (int n = 0; n < 4; ++n)
#pragma unroll
      for (int r2 = 0; r2 < 4; ++r2) {
        float v = acc[m][n][r2] + bc[n];
        if (RELU) v = fmaxf(v, 0.f);
        Cs[(wm * 64 + m * 16 + l4 * 4 + r2) * 136 + wn * 64 + n * 16 + l15] =
            (short)f2bf(v);
      }
  __syncthreads();
#pragma unroll
  for (int it = 0; it < 8; ++it) {
    int chunk = it * 512 + tid;
    int r = chunk >> 4;
    int c = (chunk & 15) << 3;
    int4 v = *(const int4*)(Cs + r * 136 + c);
    *(int4*)(C + (size_t)(bm + r) * N + bn + c) = v;
  }
}

// ---------------------------------------------------------------------------
// prep_all: ALL weight/bias prep + l=63 gather in ONE dispatch.
// Block ranges (256 threads each):
//   [0,1792)    : 7x 512x512 f32->bf16 transposes
//   [1792,2816) : build block-diag Wqk from cWk
//   [2816,3840) : mW1 transpose (K=512,N=2048)
//   [3840,4864) : mW2 transpose (K=2048,N=512)
//   [4864,4886) : bias pack (biqkv, qz zeros)
//   [4886,5078) : gather l=63 rows of ex -> G768 (4 groups/block)
// ---------------------------------------------------------------------------
__global__ __launch_bounds__(256) void prep_all(
    const float* __restrict__ ex,
    const float* __restrict__ cWq, const float* __restrict__ cWk,
    const float* __restrict__ cWv, const float* __restrict__ cWo,
    const float* __restrict__ iWq, const float* __restrict__ iWk,
    const float* __restrict__ iWv, const float* __restrict__ iWo,
    const float* __restrict__ mW1, const float* __restrict__ mW2,
    const float* __restrict__ ibq, const float* __restrict__ ibk,
    const float* __restrict__ ibv,
    ushort_t* wq, ushort_t* wv, ushort_t* wo, ushort_t* wiqkv, ushort_t* wio,
    ushort_t* w1, ushort_t* w2, ushort_t* Wqk,
    float* biqkv, float* qz, ushort_t* G768) {
  __shared__ float tile[32][33];
  const int bid = blockIdx.x;
  const int tid = threadIdx.x;

  auto do_transpose = [&](const float* W, ushort_t* Wt, int k0, int n0,
                          int Nsrc, int Kdst) {
    const int tx = tid & 31, ty = tid >> 5;
#pragma unroll
    for (int i = 0; i < 4; ++i)
      tile[ty + i * 8][tx] = W[(size_t)(k0 + ty + i * 8) * Nsrc + n0 + tx];
    __syncthreads();
#pragma unroll
    for (int i = 0; i < 4; ++i)
      Wt[(size_t)(n0 + ty + i * 8) * Kdst + k0 + tx] = f2bf(tile[tx][ty + i * 8]);
  };

  if (bid < 1792) {
    const float* srcs[7] = {cWq, cWv, cWo, iWq, iWk, iWv, iWo};
    ushort_t* dsts[7] = {wq, wv, wo, wiqkv, wiqkv + 262144, wiqkv + 524288, wio};
    const int z = bid >> 8, within = bid & 255;
    do_transpose(srcs[z], dsts[z], (within & 15) * 32, (within >> 4) * 32, 512, 512);
  } else if (bid < 2816) {
    int idx = (bid - 1792) * 256 + tid;   // 0..262143
    int n = idx >> 6;          // row 0..4095
    int c = (idx & 63) * 8;    // col 0..504
    int h = n >> 9, k = n & 511;
    union { unsigned short u[8]; int4 v; } pk;
    if ((c >> 6) == h) {
      float4 a = *(const float4*)(cWk + (size_t)k * 512 + c);
      float4 b = *(const float4*)(cWk + (size_t)k * 512 + c + 4);
      pk.u[0] = f2bf(a.x); pk.u[1] = f2bf(a.y); pk.u[2] = f2bf(a.z); pk.u[3] = f2bf(a.w);
      pk.u[4] = f2bf(b.x); pk.u[5] = f2bf(b.y); pk.u[6] = f2bf(b.z); pk.u[7] = f2bf(b.w);
    } else {
      pk.v = make_int4(0, 0, 0, 0);
    }
    *(int4*)(Wqk + (size_t)n * 512 + c) = pk.v;
  } else if (bid < 3840) {
    int b = bid - 2816;   // grid was (16,64): x=k, y=n
    do_transpose(mW1, w1, (b & 15) * 32, (b >> 4) * 32, 2048, 512);
  } else if (bid < 4864) {
    int b = bid - 3840;   // grid was (64,16)
    do_transpose(mW2, w2, (b & 63) * 32, (b >> 6) * 32, 512, 2048);
  } else if (bid < 4886) {
    int i = (bid - 4864) * 256 + tid;   // 0..5631
    if (i < 512) biqkv[i] = ibq[i];
    else if (i < 1024) biqkv[i] = ibk[i - 512];
    else if (i < 1536) biqkv[i] = ibv[i - 1024];
    else if (i < 5632) qz[i - 1536] = 0.f;
  } else {
    int g = (bid - 4886) * 4 + (tid >> 6);
    int lane = tid & 63;
    const float* src = ex + ((size_t)g * 64 + 63) * 512 + lane * 8;
    float4 a = *(const float4*)src, b = *(const float4*)(src + 4);
    union { unsigned short u[8]; int4 v; } pk;
    pk.u[0] = f2bf(a.x); pk.u[1] = f2bf(a.y); pk.u[2] = f2bf(a.z); pk.u[3] = f2bf(a.w);
    pk.u[4] = f2bf(b.x); pk.u[5] = f2bf(b.y); pk.u[6] = f2bf(b.z); pk.u[7] = f2bf(b.w);
    *(int4*)(G768 + (size_t)g * 512 + lane * 8) = pk.v;
  }
}

// ---------------------------------------------------------------------------
// Fused low-rank attention over L (512 threads, MFMA scores; proven round-14).
// ---------------------------------------------------------------------------
__global__ __launch_bounds__(512, 4) void attn_fused(
    const float* __restrict__ ex, const ushort_t* __restrict__ QW,
    ushort_t* __restrict__ Y) {
  __shared__ short xs[64][520];
  __shared__ short qws[8][520];
  __shared__ float ss[8][72];
  __shared__ float ps[8][72];
  const int g = blockIdx.x;
  const int tid = threadIdx.x;
  const int lane = tid & 63;
  const int w = tid >> 6;

  {
    const float* src = ex + (size_t)g * 64 * 512;
#pragma unroll
    for (int it = 0; it < 8; ++it) {
      int i = it * 512 + tid;
      int r = i >> 6, c = (i & 63) * 8;
      float4 a = *(const float4*)(src + r * 512 + c);
      float4 b = *(const float4*)(src + r * 512 + c + 4);
      union { unsigned short u[8]; int4 v; } pk;
      pk.u[0] = f2bf(a.x); pk.u[1] = f2bf(a.y); pk.u[2] = f2bf(a.z); pk.u[3] = f2bf(a.w);
      pk.u[4] = f2bf(b.x); pk.u[5] = f2bf(b.y); pk.u[6] = f2bf(b.z); pk.u[7] = f2bf(b.w);
      *(int4*)(&xs[r][c]) = pk.v;
    }
    int h = tid >> 6, k0 = (tid & 63) * 8;
    *(int4*)(&qws[h][k0]) = *(const int4*)(QW + (size_t)g * 4096 + tid * 8);
  }
  __syncthreads();

  if (w < 4) {
    f32x4 acc = {0.f, 0.f, 0.f, 0.f};
    const int arow = lane & 7;
    const int koff = (lane >> 4) * 8;
    const short* xrow = &xs[16 * w + (lane & 15)][0];
#pragma unroll
    for (int ks = 0; ks < 16; ++ks) {
      bf16x8 av = *(const bf16x8*)(&qws[arow][ks * 32 + koff]);
      bf16x8 bv = *(const bf16x8*)(xrow + ks * 32 + koff);
      acc = __builtin_amdgcn_mfma_f32_16x16x32_bf16(av, bv, acc, 0, 0, 0);
    }
    int t = 16 * w + (lane & 15);
    int hbase = (lane >> 4) * 4;
#pragma unroll
    for (int r = 0; r < 4; ++r) {
      int h = hbase + r;
      if (h < 8) ss[h][t] = acc[r] * 0.125f;
    }
  }
  __syncthreads();

  if (tid < 256) {
    int h = tid >> 5, t0 = tid & 31;
    float v0 = ss[h][t0], v1 = ss[h][t0 + 32];
    float mx = fmaxf(v0, v1);
#pragma unroll
    for (int o = 16; o > 0; o >>= 1) mx = fmaxf(mx, __shfl_xor(mx, o));
    float e0 = __expf(v0 - mx), e1 = __expf(v1 - mx);
    float sum = e0 + e1;
#pragma unroll
    for (int o = 16; o > 0; o >>= 1) sum += __shfl_xor(sum, o);
    float inv = 1.f / sum;
    ps[h][t0] = e0 * inv;
    ps[h][t0 + 32] = e1 * inv;
  }
  __syncthreads();

  {
    const int k0 = lane * 8;
    float acc[8] = {};
#pragma unroll
    for (int t = 0; t < 64; ++t) {
      float p = ps[w][t];
      bf16x8 xv = *(const bf16x8*)(&xs[t][k0]);
#pragma unroll
      for (int j = 0; j < 8; ++j) acc[j] += p * bf2f((unsigned short)xv[j]);
    }
    union { unsigned short u[8]; int4 v; } pk;
#pragma unroll
    for (int j = 0; j < 8; ++j) pk.u[j] = f2bf(acc[j]);
    *(int4*)(Y + ((size_t)g * 8 + w) * 512 + k0) = pk.v;
  }
}

// ---------------------------------------------------------------------------
// Attention over context axis (S=8, dh=64) on the 768-row set.
// ---------------------------------------------------------------------------
__global__ __launch_bounds__(64) void attn_ctx(
    const ushort_t* __restrict__ QKV, ushort_t* __restrict__ O) {
  __shared__ float qs[8][72], ks[8][72], vsm[8][72], ps2[8][9];
  const int h = blockIdx.x & 7;
  const int pb = blockIdx.x >> 3;   // 0..95
  const int row0 = pb * 8;
  const int tid = threadIdx.x;
  {
    int c = tid >> 3, dc = (tid & 7) * 8;
    size_t r = (size_t)(row0 + c) * 1536 + h * 64 + dc;
    int4 qv = *(const int4*)(QKV + r);
    int4 kv = *(const int4*)(QKV + r + 512);
    int4 vv = *(const int4*)(QKV + r + 1024);
    unp2(qv.x, qs[c][dc + 0], qs[c][dc + 1]); unp2(qv.y, qs[c][dc + 2], qs[c][dc + 3]);
    unp2(qv.z, qs[c][dc + 4], qs[c][dc + 5]); unp2(qv.w, qs[c][dc + 6], qs[c][dc + 7]);
    unp2(kv.x, ks[c][dc + 0], ks[c][dc + 1]); unp2(kv.y, ks[c][dc + 2], ks[c][dc + 3]);
    unp2(kv.z, ks[c][dc + 4], ks[c][dc + 5]); unp2(kv.w, ks[c][dc + 6], ks[c][dc + 7]);
    unp2(vv.x, vsm[c][dc + 0], vsm[c][dc + 1]); unp2(vv.y, vsm[c][dc + 2], vsm[c][dc + 3]);
    unp2(vv.z, vsm[c][dc + 4], vsm[c][dc + 5]); unp2(vv.w, vsm[c][dc + 6], vsm[c][dc + 7]);
  }
  __syncthreads();
  {
    int i = tid >> 3, t = tid & 7;
    float s = 0.f;
#pragma unroll
    for (int d = 0; d < 64; ++d) s += qs[i][d] * ks[t][d];
    ps2[i][t] = s * 0.125f;
  }
  __syncthreads();
  if (tid < 8) {
    float mx = -1e30f;
#pragma unroll
    for (int t = 0; t < 8; ++t) mx = fmaxf(mx, ps2[tid][t]);
    float sum = 0.f;
#pragma unroll
    for (int t = 0; t < 8; ++t) { float e = __expf(ps2[tid][t] - mx); ps2[tid][t] = e; sum += e; }
    float inv = 1.f / sum;
#pragma unroll
    for (int t = 0; t < 8; ++t) ps2[tid][t] *= inv;
  }
  __syncthreads();
#pragma unroll
  for (int c = 0; c < 8; ++c) {
    float s = 0.f;
#pragma unroll
    for (int t = 0; t < 8; ++t) s += ps2[c][t] * vsm[t][tid];
    O[(size_t)(row0 + c) * 512 + h * 64 + tid] = f2bf(s);
  }
}

// ---------------------------------------------------------------------------
// Xout(bf16) = LN(Xin_row + T) * g + b.  Xin row at blockIdx.x*in_stride+in_base.
// ---------------------------------------------------------------------------
template <bool INF32>
__global__ __launch_bounds__(256) void add_ln(
    const void* Xin, size_t in_stride, size_t in_base,
    const ushort_t* T, ushort_t* Xout,
    const float* __restrict__ g, const float* __restrict__ b) {
  const size_t off = (size_t)blockIdx.x * D_;
  const size_t ioff = (size_t)blockIdx.x * in_stride + in_base;
  const int tid = threadIdx.x;
  float x0, x1;
  if (INF32) {
    float2 xv = ((const float2*)((const float*)Xin + ioff))[tid];
    x0 = xv.x; x1 = xv.y;
  } else {
    ushort2 xv = ((const ushort2*)((const ushort_t*)Xin + ioff))[tid];
    x0 = bf2f(xv.x); x1 = bf2f(xv.y);
  }
  ushort2 tv = ((const ushort2*)(T + off))[tid];
  x0 += bf2f(tv.x);
  x1 += bf2f(tv.y);
  float s = x0 + x1, q = x0 * x0 + x1 * x1;
#pragma unroll
  for (int o = 32; o > 0; o >>= 1) { s += __shfl_down(s, o); q += __shfl_down(q, o); }
  __shared__ float ssum[4], sqsum[4];
  if ((tid & 63) == 0) { ssum[tid >> 6] = s; sqsum[tid >> 6] = q; }
  __syncthreads();
  float S = ssum[0] + ssum[1] + ssum[2] + ssum[3];
  float Qs = sqsum[0] + sqsum[1] + sqsum[2] + sqsum[3];
  float m = S * (1.f / D_);
  float var = Qs * (1.f / D_) - m * m;
  float inv = rsqrtf(var + 1e-5f);
  float y0 = (x0 - m) * inv * g[tid * 2] + b[tid * 2];
  float y1 = (x1 - m) * inv * g[tid * 2 + 1] + b[tid * 2 + 1];
  ushort2 ov; ov.x = f2bf(y0); ov.y = f2bf(y1);
  ((ushort2*)(Xout + off))[tid] = ov;
}

// ---------------------------------------------------------------------------
// Final fusion: per (b,c): 6x LN(X+P row) -> gated sum -> head matvec.
// ---------------------------------------------------------------------------
__global__ __launch_bounds__(256) void final_fuse(
    const ushort_t* __restrict__ X, const ushort_t* __restrict__ P,
    const float* __restrict__ gates,
    const float* __restrict__ g4, const float* __restrict__ b4,
    const float* __restrict__ hW, const float* __restrict__ hb,
    float* __restrict__ out) {
  __shared__ float xr[D_];
  __shared__ float ssum[4], sqsum[4];
  const int bb = blockIdx.x >> 3, cc = blockIdx.x & 7;
  const int tid = threadIdx.x;
  const float gw0 = g4[tid * 2], gw1 = g4[tid * 2 + 1];
  const float bw0 = b4[tid * 2], bw1 = b4[tid * 2 + 1];
  float a0 = 0.f, a1 = 0.f;
#pragma unroll
  for (int p = 0; p < PS; ++p) {
    const size_t row = ((size_t)(p * BB + bb) * CC + cc) * D_;
    ushort2 xv = ((const ushort2*)(X + row))[tid];
    ushort2 tv = ((const ushort2*)(P + row))[tid];
    float x0 = bf2f(xv.x) + bf2f(tv.x);
    float x1 = bf2f(xv.y) + bf2f(tv.y);
    float s = x0 + x1, q = x0 * x0 + x1 * x1;
#pragma unroll
    for (int o = 32; o > 0; o >>= 1) { s += __shfl_down(s, o); q += __shfl_down(q, o); }
    if ((tid & 63) == 0) { ssum[tid >> 6] = s; sqsum[tid >> 6] = q; }
    __syncthreads();
    float S = ssum[0] + ssum[1] + ssum[2] + ssum[3];
    float Qs = sqsum[0] + sqsum[1] + sqsum[2] + sqsum[3];
    float m = S * (1.f / D_);
    float var = Qs * (1.f / D_) - m * m;
    float inv = rsqrtf(var + 1e-5f);
    float gate = gates[bb * PS + p];
    a0 += gate * ((x0 - m) * inv * gw0 + bw0);
    a1 += gate * ((x1 - m) * inv * gw1 + bw1);
    __syncthreads();
  }
  xr[tid * 2] = a0;
  xr[tid * 2 + 1] = a1;
  __syncthreads();
  if (tid < PREDN) {
    float s = hb[tid];
    for (int d = 0; d < D_; ++d) s += xr[d] * hW[d * PREDN + tid];
    out[((size_t)bb * PREDN + tid) * CC + cc] = s;
  }
}

// ---------------------------------------------------------------------------
extern "C" void kernel_launch(void* const* d_in, const int* in_sizes, int n_in,
                              void* d_out, int out_size, void* d_ws, size_t ws_size,
                              hipStream_t stream) {
  const float* ex    = (const float*)d_in[0];
  const float* gates = (const float*)d_in[1];
  const float* cWq = (const float*)d_in[2];  const float* cbq = (const float*)d_in[3];
  const float* cWk = (const float*)d_in[4];  const float* cbk = (const float*)d_in[5];
  const float* cWv = (const float*)d_in[6];  const float* cbv = (const float*)d_in[7];
  const float* cWo = (const float*)d_in[8];  const float* cbo = (const float*)d_in[9];
  const float* iWq = (const float*)d_in[10]; const float* ibq = (const float*)d_in[11];
  const float* iWk = (const float*)d_in[12]; const float* ibk = (const float*)d_in[13];
  const float* iWv = (const float*)d_in[14]; const float* ibv = (const float*)d_in[15];
  const float* iWo = (const float*)d_in[16]; const float* ibo = (const float*)d_in[17];
  const float* mW1 = (const float*)d_in[18]; const float* mb1 = (const float*)d_in[19];
  const float* mW2 = (const float*)d_in[20]; const float* mb2 = (const float*)d_in[21];
  const float* g1  = (const float*)d_in[22]; const float* b1  = (const float*)d_in[23];
  const float* g3  = (const float*)d_in[24]; const float* b3  = (const float*)d_in[25];
  const float* g4  = (const float*)d_in[26]; const float* b4  = (const float*)d_in[27];
  const float* hW  = (const float*)d_in[28]; const float* hb  = (const float*)d_in[29];
  float* out = (float*)d_out;

  // ---- workspace layout (shorts unless noted) ----
  ushort_t* wq    = (ushort_t*)d_ws;           // [512][512]  cWq^T
  ushort_t* wv    = wq + 262144;               // [512][512]  cWv^T
  ushort_t* wo    = wv + 262144;               // [512][512]  cWo^T
  ushort_t* wiqkv = wo + 262144;               // [1536][512]
  ushort_t* wio   = wiqkv + 786432;            // [512][512]
  ushort_t* w1    = wio + 262144;              // [2048][512]
  ushort_t* w2    = w1 + 1048576;              // [512][2048]
  ushort_t* Wqk   = w2 + 1048576;              // [4096][512] block-diag cWk
  float* biqkv = (float*)(Wqk + 2097152);      // [1536] ibq|ibk|ibv
  float* qz    = biqkv + 1536;                 // [4096] zeros
  ushort_t* G768   = (ushort_t*)(qz + 4096);   // [NG][512]
  ushort_t* Q768   = G768 + (size_t)NG * 512;  // [NG][512]
  ushort_t* QW     = Q768 + (size_t)NG * 512;  // [NG][4096]
  ushort_t* Yb     = QW + (size_t)NG * 4096;   // [NG*8][512]
  ushort_t* Tbuf   = Yb + (size_t)NG * 4096;   // [NG*8][512]
  ushort_t* O768   = Tbuf + (size_t)NG * 4096; // [NG][512]
  ushort_t* P768   = O768 + (size_t)NG * 512;  // [NG][512]
  ushort_t* X768   = P768 + (size_t)NG * 512;  // [NG][512]
  ushort_t* QKV768 = X768 + (size_t)NG * 512;  // [NG][1536]
  ushort_t* H768   = QKV768 + (size_t)NG * 1536; // [NG][2048]

  // ---- all prep + l=63 gather: ONE dispatch ----
  prep_all<<<dim3(5078), dim3(256), 0, stream>>>(
      ex, cWq, cWk, cWv, cWo, iWq, iWk, iWv, iWo, mW1, mW2,
      ibq, ibk, ibv,
      wq, wv, wo, wiqkv, wio, w1, w2, Wqk, biqkv, qz, G768);

  // ---- block 1: low-rank attention over L ----
  gemm_mfma<false, false><<<dim3(3 * 4), dim3(512), 0, stream>>>(G768, wq, cbq, Q768, NG, 512, 512);
  gemm_mfma<false, false><<<dim3(3 * 32), dim3(512), 0, stream>>>(Q768, Wqk, qz, QW, NG, 4096, 512);
  attn_fused<<<dim3(NG), dim3(512), 0, stream>>>(ex, QW, Yb);
  gemm_mfma<false, false><<<dim3(24 * 4), dim3(512), 0, stream>>>(Yb, wv, cbv, Tbuf, NG * 8, 512, 512);
  // O-projection reads the diagonal head-blocks of Tbuf directly (DIAGA)
  gemm_mfma<false, true><<<dim3(3 * 4), dim3(512), 0, stream>>>(Tbuf, wo, cbo, P768, NG, 512, 512);
  add_ln<true><<<dim3(NG), dim3(256), 0, stream>>>(
      ex, (size_t)(LL * D_), (size_t)((LL - 1) * D_), P768, X768, g1, b1);

  // ---- block 2: attention over C ----
  gemm_mfma<false, false><<<dim3(3 * 12), dim3(512), 0, stream>>>(X768, wiqkv, biqkv, QKV768, NG, 1536, 512);
  attn_ctx<<<dim3(96 * 8), dim3(64), 0, stream>>>(QKV768, O768);
  gemm_mfma<false, false><<<dim3(3 * 4), dim3(512), 0, stream>>>(O768, wio, ibo, P768, NG, 512, 512);
  add_ln<false><<<dim3(NG), dim3(256), 0, stream>>>(
      X768, (size_t)D_, (size_t)0, P768, X768, g3, b3);

  // ---- MLP ----
  gemm_mfma<true,  false><<<dim3(3 * 16), dim3(512), 0, stream>>>(X768, w1, mb1, H768, NG, 2048, 512);
  gemm_mfma<false, false><<<dim3(3 * 4), dim3(512), 0, stream>>>(H768, w2, mb2, P768, NG, 512, 2048);

  // ---- fused final LN + gated combine + head ----
  final_fuse<<<dim3(BB * CC), dim3(256), 0, stream>>>(
      X768, P768, gates, g4, b4, hW, hb, out);
}